// Round 3
// baseline (2406.223 us; speedup 1.0000x reference)
//
#include <hip/hip_runtime.h>
#include <hip/hip_bf16.h>
#include <math.h>

// ---------------------------------------------------------------------------
// EEG-ViT forward, fp32 baseline (round 3 re-land; broker timeouts r0-r2,
// kernel has never executed). Desk-checked vs reference.
// Kernel 1 (proj_kernel): patchify + projection GEMM -> token buffer in d_ws
//   x0[b][s][d], s=0 cls, s=1..5 patches, includes +proj_b, +cls, +pe.
// Kernel 2 (tf_kernel): 6 transformer layers fully fused, one wave per sample
//   (lane = feature d), LN via 64-lane shfl reductions, per-sample scratch in
//   LDS, weights streamed from global (L1/L2-resident, lockstep across the
//   block's 4 waves), head + softmax at the end.
// ---------------------------------------------------------------------------

#define B_TOT   16384
#define SEQ     6
#define DMODEL  64
#define NLAYER  6

// ---------------- Kernel 1: projection ----------------
// rows = (sample, patch): out[row][d] = sum_k x[b, addr(k,p)] * W[k][d]
// k = h*25+t  ->  input offset h*125 + p*25 + t
#define PKC 160              // K-chunk
#define ROWS_PER_BLK 40      // 8 samples x 5 patches
#define SMP_PER_BLK 8

__global__ __launch_bounds__(256) void proj_kernel(
    const float* __restrict__ xin,   // (B, 8000)
    const float* __restrict__ Wp,    // (1600, 64)
    const float* __restrict__ pb,    // (64)
    const float* __restrict__ cls,   // (64)
    const float* __restrict__ pe,    // (6)
    float* __restrict__ x0)          // (B, 6, 64)
{
    __shared__ float wlds[PKC][64];
    __shared__ float xlds[ROWS_PER_BLK][PKC];

    const int tid  = threadIdx.x;
    const int lane = tid & 63;
    const int wv   = tid >> 6;          // wave id 0..3, handles rows wv*10..wv*10+9
    const int b0   = blockIdx.x * SMP_PER_BLK;

    float acc[10];
#pragma unroll
    for (int r = 0; r < 10; ++r) acc[r] = 0.f;

    for (int kc = 0; kc < 1600; kc += PKC) {
        // stage W chunk (contiguous rows of W) via float4
        {
            const float4* wsrc = (const float4*)(Wp + (size_t)kc * 64);
            float4* wdst = (float4*)(&wlds[0][0]);
#pragma unroll
            for (int i = 0; i < (PKC * 64 / 4) / 256; ++i)
                wdst[tid + i * 256] = wsrc[tid + i * 256];
        }
        // stage x chunk (gathered by patchify mapping)
        for (int i = tid; i < ROWS_PER_BLK * PKC; i += 256) {
            int row = i / PKC;
            int kk  = i - row * PKC;
            int k   = kc + kk;
            int smp = row / 5;
            int p   = row - smp * 5;
            int h   = k / 25;
            int t   = k - h * 25;
            xlds[row][kk] = xin[(size_t)(b0 + smp) * 8000 + h * 125 + p * 25 + t];
        }
        __syncthreads();

        // compute: lane = output feature d
        for (int kk = 0; kk < PKC; kk += 4) {
            float w0 = wlds[kk + 0][lane];
            float w1 = wlds[kk + 1][lane];
            float w2 = wlds[kk + 2][lane];
            float w3 = wlds[kk + 3][lane];
#pragma unroll
            for (int r = 0; r < 10; ++r) {
                const float* xr = &xlds[wv * 10 + r][kk];  // contiguous -> b128
                acc[r] += xr[0] * w0 + xr[1] * w1 + xr[2] * w2 + xr[3] * w3;
            }
        }
        __syncthreads();
    }

    const float bias = pb[lane];
    const float peP[5] = {pe[1], pe[2], pe[3], pe[4], pe[5]};
#pragma unroll
    for (int r = 0; r < 10; ++r) {
        int row = wv * 10 + r;
        int smp = row / 5;
        int p   = row - smp * 5;
        x0[((size_t)(b0 + smp) * SEQ + (p + 1)) * 64 + lane] = acc[r] + bias + peP[p];
    }
    // cls rows: 8 samples, 2 per wave
    float cv = cls[lane] + pe[0];
    x0[((size_t)(b0 + wv * 2 + 0) * SEQ) * 64 + lane] = cv;
    x0[((size_t)(b0 + wv * 2 + 1) * SEQ) * 64 + lane] = cv;
}

// ---------------- Kernel 2: fused transformer ----------------

__device__ __forceinline__ float wred(float v) {
#pragma unroll
    for (int o = 32; o > 0; o >>= 1) v += __shfl_xor(v, o, 64);
    return v;
}

#define SMP_TF 4   // samples (=waves) per block

__global__ __launch_bounds__(256) void tf_kernel(
    const float* __restrict__ x0buf,
    const float* __restrict__ qkv_w, const float* __restrict__ qkv_b,
    const float* __restrict__ out_w, const float* __restrict__ out_b,
    const float* __restrict__ ln1_g, const float* __restrict__ ln1_b,
    const float* __restrict__ ln2_g, const float* __restrict__ ln2_b,
    const float* __restrict__ mlp_w1, const float* __restrict__ mlp_b1,
    const float* __restrict__ mlp_w2, const float* __restrict__ mlp_b2,
    const float* __restrict__ head_g, const float* __restrict__ head_b,
    const float* __restrict__ head_w, const float* __restrict__ head_bias,
    float* __restrict__ out)
{
    __shared__ float h_lds[SMP_TF][SEQ][64];
    __shared__ float qkv_lds[SMP_TF][SEQ][192];
    __shared__ float o_lds[SMP_TF][SEQ][64];
    __shared__ float att_lds[SMP_TF][4][SEQ][SEQ];
    __shared__ float m_lds[SMP_TF][SEQ][128];

    const int lane = threadIdx.x & 63;
    const int w    = threadIdx.x >> 6;
    const int b    = blockIdx.x * SMP_TF + w;

    float x[SEQ];
#pragma unroll
    for (int s = 0; s < SEQ; ++s)
        x[s] = x0buf[((size_t)b * SEQ + s) * 64 + lane];

    for (int l = 0; l < NLAYER; ++l) {
        // ---- LN1 ----
        {
            float g = ln1_g[l * 64 + lane], bb = ln1_b[l * 64 + lane];
#pragma unroll
            for (int s = 0; s < SEQ; ++s) {
                float val = x[s];
                float m   = wred(val) * (1.f / 64.f);
                float dv  = val - m;
                float var = wred(dv * dv) * (1.f / 64.f);
                h_lds[w][s][lane] = dv * rsqrtf(var + 1e-5f) * g + bb;
            }
        }
        __syncthreads();

        // ---- QKV ----
        {
            const float* Wq = qkv_w + (size_t)l * 64 * 192;
#pragma unroll
            for (int c = 0; c < 3; ++c) {
                float acc[SEQ];
#pragma unroll
                for (int s = 0; s < SEQ; ++s) acc[s] = 0.f;
#pragma unroll 4
                for (int d = 0; d < 64; ++d) {
                    float wvv = Wq[d * 192 + c * 64 + lane];
#pragma unroll
                    for (int s = 0; s < SEQ; ++s) acc[s] += h_lds[w][s][d] * wvv;
                }
                float bias = qkv_b[l * 192 + c * 64 + lane];
#pragma unroll
                for (int s = 0; s < SEQ; ++s)
                    qkv_lds[w][s][c * 64 + lane] = acc[s] + bias;
            }
        }
        __syncthreads();

        // ---- scores + softmax (lanes 0..23: lane = s*4 + n) ----
        if (lane < 24) {
            int n = lane & 3;
            int s = lane >> 2;
            float sc[SEQ];
#pragma unroll
            for (int t = 0; t < SEQ; ++t) {
                float dot = 0.f;
#pragma unroll
                for (int dh = 0; dh < 16; ++dh)
                    dot += qkv_lds[w][s][n * 16 + dh] * qkv_lds[w][t][64 + n * 16 + dh];
                sc[t] = dot * 0.25f;  // DH^-0.5
            }
            float mx = sc[0];
#pragma unroll
            for (int t = 1; t < SEQ; ++t) mx = fmaxf(mx, sc[t]);
            float e[SEQ], sum = 0.f;
#pragma unroll
            for (int t = 0; t < SEQ; ++t) { e[t] = __expf(sc[t] - mx); sum += e[t]; }
            float inv = 1.f / sum;
#pragma unroll
            for (int t = 0; t < SEQ; ++t) att_lds[w][n][s][t] = e[t] * inv;
        }
        __syncthreads();

        // ---- o = att @ v ----
        {
            int n = lane >> 4;
#pragma unroll
            for (int s = 0; s < SEQ; ++s) {
                float acc = 0.f;
#pragma unroll
                for (int t = 0; t < SEQ; ++t)
                    acc += att_lds[w][n][s][t] * qkv_lds[w][t][128 + lane];
                o_lds[w][s][lane] = acc;
            }
        }
        __syncthreads();

        // ---- out proj + residual ----
        {
            const float* Wo = out_w + (size_t)l * 64 * 64;
            float acc[SEQ];
#pragma unroll
            for (int s = 0; s < SEQ; ++s) acc[s] = 0.f;
#pragma unroll 4
            for (int j = 0; j < 64; ++j) {
                float wvv = Wo[j * 64 + lane];
#pragma unroll
                for (int s = 0; s < SEQ; ++s) acc[s] += o_lds[w][s][j] * wvv;
            }
            float bias = out_b[l * 64 + lane];
#pragma unroll
            for (int s = 0; s < SEQ; ++s) x[s] += acc[s] + bias;
        }
        __syncthreads();

        // ---- LN2 ----
        {
            float g = ln2_g[l * 64 + lane], bb = ln2_b[l * 64 + lane];
#pragma unroll
            for (int s = 0; s < SEQ; ++s) {
                float val = x[s];
                float m   = wred(val) * (1.f / 64.f);
                float dv  = val - m;
                float var = wred(dv * dv) * (1.f / 64.f);
                h_lds[w][s][lane] = dv * rsqrtf(var + 1e-5f) * g + bb;
            }
        }
        __syncthreads();

        // ---- MLP1 + exact GELU ----
        {
            const float* W1 = mlp_w1 + (size_t)l * 64 * 128;
#pragma unroll
            for (int c = 0; c < 2; ++c) {
                float acc[SEQ];
#pragma unroll
                for (int s = 0; s < SEQ; ++s) acc[s] = 0.f;
#pragma unroll 4
                for (int d = 0; d < 64; ++d) {
                    float wvv = W1[d * 128 + c * 64 + lane];
#pragma unroll
                    for (int s = 0; s < SEQ; ++s) acc[s] += h_lds[w][s][d] * wvv;
                }
                float bias = mlp_b1[l * 128 + c * 64 + lane];
#pragma unroll
                for (int s = 0; s < SEQ; ++s) {
                    float u = acc[s] + bias;
                    m_lds[w][s][c * 64 + lane] = 0.5f * u * (1.f + erff(u * 0.70710678118654752f));
                }
            }
        }
        __syncthreads();

        // ---- MLP2 + residual ----
        {
            const float* W2 = mlp_w2 + (size_t)l * 128 * 64;
            float acc[SEQ];
#pragma unroll
            for (int s = 0; s < SEQ; ++s) acc[s] = 0.f;
#pragma unroll 4
            for (int j = 0; j < 128; ++j) {
                float wvv = W2[j * 64 + lane];
#pragma unroll
                for (int s = 0; s < SEQ; ++s) acc[s] += m_lds[w][s][j] * wvv;
            }
            float bias = mlp_b2[l * 64 + lane];
#pragma unroll
            for (int s = 0; s < SEQ; ++s) x[s] += acc[s] + bias;
        }
        __syncthreads();
    }

    // ---- head: LN(cls) @ head_w -> softmax(2) ----
    {
        float val = x[0];
        float m   = wred(val) * (1.f / 64.f);
        float dv  = val - m;
        float var = wred(dv * dv) * (1.f / 64.f);
        float hh  = dv * rsqrtf(var + 1e-5f) * head_g[lane] + head_b[lane];
        float l0  = wred(hh * head_w[lane * 2 + 0]);
        float l1  = wred(hh * head_w[lane * 2 + 1]);
        if (lane == 0) {
            l0 += head_bias[0];
            l1 += head_bias[1];
            float mx = fmaxf(l0, l1);
            float e0 = __expf(l0 - mx), e1 = __expf(l1 - mx);
            float inv = 1.f / (e0 + e1);
            out[(size_t)b * 2 + 0] = e0 * inv;
            out[(size_t)b * 2 + 1] = e1 * inv;
        }
    }
}

// ---------------- launch ----------------
extern "C" void kernel_launch(void* const* d_in, const int* in_sizes, int n_in,
                              void* d_out, int out_size, void* d_ws, size_t ws_size,
                              hipStream_t stream) {
    const float* xin     = (const float*)d_in[0];
    const float* proj_w  = (const float*)d_in[1];
    const float* proj_b  = (const float*)d_in[2];
    const float* cls     = (const float*)d_in[3];
    const float* pe      = (const float*)d_in[4];
    const float* qkv_w   = (const float*)d_in[5];
    const float* qkv_b   = (const float*)d_in[6];
    const float* out_w   = (const float*)d_in[7];
    const float* out_b   = (const float*)d_in[8];
    const float* ln1_g   = (const float*)d_in[9];
    const float* ln1_b   = (const float*)d_in[10];
    const float* ln2_g   = (const float*)d_in[11];
    const float* ln2_b   = (const float*)d_in[12];
    const float* mlp_w1  = (const float*)d_in[13];
    const float* mlp_b1  = (const float*)d_in[14];
    const float* mlp_w2  = (const float*)d_in[15];
    const float* mlp_b2  = (const float*)d_in[16];
    const float* head_g  = (const float*)d_in[17];
    const float* head_b  = (const float*)d_in[18];
    const float* head_w  = (const float*)d_in[19];
    const float* head_bs = (const float*)d_in[20];
    float* outp = (float*)d_out;

    float* x0 = (float*)d_ws;  // B*6*64 floats = 25.2 MB

    proj_kernel<<<B_TOT / SMP_PER_BLK, 256, 0, stream>>>(
        xin, proj_w, proj_b, cls, pe, x0);

    tf_kernel<<<B_TOT / SMP_TF, 256, 0, stream>>>(
        x0, qkv_w, qkv_b, out_w, out_b, ln1_g, ln1_b, ln2_g, ln2_b,
        mlp_w1, mlp_b1, mlp_w2, mlp_b2, head_g, head_b, head_w, head_bs, outp);
}

// Round 4
// 2141.701 us; speedup vs baseline: 1.1235x; 1.1235x over previous
//
#include <hip/hip_runtime.h>
#include <hip/hip_bf16.h>
#include <math.h>

// ---------------------------------------------------------------------------
// EEG-ViT forward. Round 4.
// proj_kernel v2: register-blocked fp32 micro-tile GEMM (lane = 4 rows x 8
//   cols), double-buffered LDS for x (patchify-gathered via 13 precomputed
//   per-thread offsets) and W (coalesced float4). One barrier per h-step.
// tf_kernel: UNCHANGED from validated bit-exact baseline (1318 us).
// ---------------------------------------------------------------------------

#define B_TOT   16384
#define SEQ     6
#define NLAYER  6

typedef float f4 __attribute__((ext_vector_type(4)));

// ---------------- Kernel 1: projection (micro-tile) ----------------
// out[row][d] = sum_k x[b, h*125 + p*25 + t] * W[k][d],  k = h*25+t
// row = smp*5+p (81920 rows), d = 0..63.
#define PROJ_BLOCKS 640
#define ROWS_BLK    128          // patch-rows per block (4 waves x 32 rows)
#define XSTR        28           // xlds row stride in floats (25 padded to 16B mult)

__global__ __launch_bounds__(256) void proj_kernel(
    const float* __restrict__ xin,   // (B, 8000)
    const float* __restrict__ Wp,    // (1600, 64)
    const float* __restrict__ pb,    // (64)
    const float* __restrict__ cls,   // (64)
    const float* __restrict__ pe,    // (6)
    float* __restrict__ x0)          // (B, 6, 64)
{
    const int tid  = threadIdx.x;
    const int blk  = blockIdx.x;

    if (blk >= PROJ_BLOCKS) {
        // ---- cls rows: x0[b][0][d] = cls[d] + pe[0], 16 blocks ----
        const float pe0 = pe[0];
        const f4* cls4 = (const f4*)cls;
        f4 cv[16];
#pragma unroll
        for (int j = 0; j < 16; ++j) cv[j] = cls4[j] + pe0;
        int r0 = (blk - PROJ_BLOCKS) * 1024 + tid * 4;
#pragma unroll
        for (int rr = 0; rr < 4; ++rr) {
            f4* dst = (f4*)(x0 + (size_t)(r0 + rr) * 384);
#pragma unroll
            for (int j = 0; j < 16; ++j) dst[j] = cv[j];
        }
        return;
    }

    __shared__ float xlds[2][ROWS_BLK * XSTR];   // 2 x 14336 B
    __shared__ float wlds[2][25 * 64];           // 2 x  6400 B

    const int lane = tid & 63;
    const int wv   = tid >> 6;
    const int rg   = lane >> 3;      // 0..7
    const int cg   = lane & 7;       // 0..7
    const int brow0 = blk * ROWS_BLK;

    // ---- staging precompute: 13 x-elements per thread ----
    // flat = tid + j*256 in [0,3200): row = flat/25, t = flat%25
    unsigned goff[13];   // global float offset (add h*125 each step)
    unsigned loff[13];   // lds float offset
#pragma unroll
    for (int j = 0; j < 13; ++j) {
        int flat = tid + j * 256;
        if (j < 12 || tid < 128) {
            int row  = flat / 25;
            int t    = flat - row * 25;
            int grow = brow0 + row;
            int smp  = grow / 5;
            int p    = grow - smp * 5;
            goff[j] = (unsigned)smp * 8000u + (unsigned)p * 25u + (unsigned)t;
            loff[j] = (unsigned)(row * XSTR + t);
        } else { goff[j] = 0u; loff[j] = 0u; }
    }

    const f4* Wp4 = (const f4*)Wp;   // 400 f4 per h-chunk

    f4 acc[4][2];
#pragma unroll
    for (int j = 0; j < 4; ++j) { acc[j][0] = (f4)0.f; acc[j][1] = (f4)0.f; }

    float xg[13];
    f4    wg[2];

    // ---- prologue: stage h=0 ----
    {
#pragma unroll
        for (int j = 0; j < 12; ++j) xg[j] = xin[goff[j]];
        if (tid < 128) xg[12] = xin[goff[12]];
        wg[0] = Wp4[tid];
        if (tid < 144) wg[1] = Wp4[256 + tid];
#pragma unroll
        for (int j = 0; j < 12; ++j) xlds[0][loff[j]] = xg[j];
        if (tid < 128) xlds[0][loff[12]] = xg[12];
        ((f4*)wlds[0])[tid] = wg[0];
        if (tid < 144) ((f4*)wlds[0])[256 + tid] = wg[1];
    }
    __syncthreads();

    const int xbase = (wv * 32 + rg * 4) * XSTR;
    const int wcol  = cg * 8;

    for (int h = 0; h < 64; ++h) {
        const int bb = h & 1;
        // ---- issue global loads for h+1 ----
        if (h < 63) {
            const unsigned gadd = (unsigned)(h + 1) * 125u;
#pragma unroll
            for (int j = 0; j < 12; ++j) xg[j] = xin[goff[j] + gadd];
            if (tid < 128) xg[12] = xin[goff[12] + gadd];
            const f4* wsrc = Wp4 + (size_t)(h + 1) * 400;
            wg[0] = wsrc[tid];
            if (tid < 144) wg[1] = wsrc[256 + tid];
        }

        // ---- compute h from buffers ----
        {
            const float* xw = &xlds[bb][xbase];
            const float* wb = &wlds[bb][wcol];
#pragma unroll
            for (int t4 = 0; t4 < 6; ++t4) {
                f4 xr[4];
#pragma unroll
                for (int j = 0; j < 4; ++j)
                    xr[j] = *(const f4*)&xw[j * XSTR + t4 * 4];
#pragma unroll
                for (int kk = 0; kk < 4; ++kk) {
                    const float* wrow = &wb[(t4 * 4 + kk) * 64];
                    f4 wa = *(const f4*)&wrow[0];
                    f4 wc = *(const f4*)&wrow[4];
#pragma unroll
                    for (int j = 0; j < 4; ++j) {
                        float xv = xr[j][kk];
                        acc[j][0] += xv * wa;
                        acc[j][1] += xv * wc;
                    }
                }
            }
            // tail t = 24
            {
                const float* wrow = &wb[24 * 64];
                f4 wa = *(const f4*)&wrow[0];
                f4 wc = *(const f4*)&wrow[4];
#pragma unroll
                for (int j = 0; j < 4; ++j) {
                    float xv = xw[j * XSTR + 24];
                    acc[j][0] += xv * wa;
                    acc[j][1] += xv * wc;
                }
            }
        }

        // ---- write staged data for h+1 ----
        if (h < 63) {
            const int nb = bb ^ 1;
#pragma unroll
            for (int j = 0; j < 12; ++j) xlds[nb][loff[j]] = xg[j];
            if (tid < 128) xlds[nb][loff[12]] = xg[12];
            ((f4*)wlds[nb])[tid] = wg[0];
            if (tid < 144) ((f4*)wlds[nb])[256 + tid] = wg[1];
        }
        __syncthreads();
    }

    // ---- epilogue: bias + pe, store ----
    const f4* pb4 = (const f4*)pb;
    f4 pbv0 = pb4[cg * 2], pbv1 = pb4[cg * 2 + 1];
#pragma unroll
    for (int j = 0; j < 4; ++j) {
        int grow = brow0 + wv * 32 + rg * 4 + j;
        int smp  = grow / 5;
        int p    = grow - smp * 5;
        float pev = pe[p + 1];
        f4 o0 = acc[j][0] + pbv0 + pev;
        f4 o1 = acc[j][1] + pbv1 + pev;
        float* dst = x0 + ((size_t)smp * SEQ + (p + 1)) * 64 + cg * 8;
        *(f4*)dst       = o0;
        *(f4*)(dst + 4) = o1;
    }
}

// ---------------- Kernel 2: fused transformer (UNCHANGED, validated) ------

__device__ __forceinline__ float wred(float v) {
#pragma unroll
    for (int o = 32; o > 0; o >>= 1) v += __shfl_xor(v, o, 64);
    return v;
}

#define SMP_TF 4   // samples (=waves) per block

__global__ __launch_bounds__(256) void tf_kernel(
    const float* __restrict__ x0buf,
    const float* __restrict__ qkv_w, const float* __restrict__ qkv_b,
    const float* __restrict__ out_w, const float* __restrict__ out_b,
    const float* __restrict__ ln1_g, const float* __restrict__ ln1_b,
    const float* __restrict__ ln2_g, const float* __restrict__ ln2_b,
    const float* __restrict__ mlp_w1, const float* __restrict__ mlp_b1,
    const float* __restrict__ mlp_w2, const float* __restrict__ mlp_b2,
    const float* __restrict__ head_g, const float* __restrict__ head_b,
    const float* __restrict__ head_w, const float* __restrict__ head_bias,
    float* __restrict__ out)
{
    __shared__ float h_lds[SMP_TF][SEQ][64];
    __shared__ float qkv_lds[SMP_TF][SEQ][192];
    __shared__ float o_lds[SMP_TF][SEQ][64];
    __shared__ float att_lds[SMP_TF][4][SEQ][SEQ];
    __shared__ float m_lds[SMP_TF][SEQ][128];

    const int lane = threadIdx.x & 63;
    const int w    = threadIdx.x >> 6;
    const int b    = blockIdx.x * SMP_TF + w;

    float x[SEQ];
#pragma unroll
    for (int s = 0; s < SEQ; ++s)
        x[s] = x0buf[((size_t)b * SEQ + s) * 64 + lane];

    for (int l = 0; l < NLAYER; ++l) {
        // ---- LN1 ----
        {
            float g = ln1_g[l * 64 + lane], bb = ln1_b[l * 64 + lane];
#pragma unroll
            for (int s = 0; s < SEQ; ++s) {
                float val = x[s];
                float m   = wred(val) * (1.f / 64.f);
                float dv  = val - m;
                float var = wred(dv * dv) * (1.f / 64.f);
                h_lds[w][s][lane] = dv * rsqrtf(var + 1e-5f) * g + bb;
            }
        }
        __syncthreads();

        // ---- QKV ----
        {
            const float* Wq = qkv_w + (size_t)l * 64 * 192;
#pragma unroll
            for (int c = 0; c < 3; ++c) {
                float acc[SEQ];
#pragma unroll
                for (int s = 0; s < SEQ; ++s) acc[s] = 0.f;
#pragma unroll 4
                for (int d = 0; d < 64; ++d) {
                    float wvv = Wq[d * 192 + c * 64 + lane];
#pragma unroll
                    for (int s = 0; s < SEQ; ++s) acc[s] += h_lds[w][s][d] * wvv;
                }
                float bias = qkv_b[l * 192 + c * 64 + lane];
#pragma unroll
                for (int s = 0; s < SEQ; ++s)
                    qkv_lds[w][s][c * 64 + lane] = acc[s] + bias;
            }
        }
        __syncthreads();

        // ---- scores + softmax (lanes 0..23: lane = s*4 + n) ----
        if (lane < 24) {
            int n = lane & 3;
            int s = lane >> 2;
            float sc[SEQ];
#pragma unroll
            for (int t = 0; t < SEQ; ++t) {
                float dot = 0.f;
#pragma unroll
                for (int dh = 0; dh < 16; ++dh)
                    dot += qkv_lds[w][s][n * 16 + dh] * qkv_lds[w][t][64 + n * 16 + dh];
                sc[t] = dot * 0.25f;  // DH^-0.5
            }
            float mx = sc[0];
#pragma unroll
            for (int t = 1; t < SEQ; ++t) mx = fmaxf(mx, sc[t]);
            float e[SEQ], sum = 0.f;
#pragma unroll
            for (int t = 0; t < SEQ; ++t) { e[t] = __expf(sc[t] - mx); sum += e[t]; }
            float inv = 1.f / sum;
#pragma unroll
            for (int t = 0; t < SEQ; ++t) att_lds[w][n][s][t] = e[t] * inv;
        }
        __syncthreads();

        // ---- o = att @ v ----
        {
            int n = lane >> 4;
#pragma unroll
            for (int s = 0; s < SEQ; ++s) {
                float acc = 0.f;
#pragma unroll
                for (int t = 0; t < SEQ; ++t)
                    acc += att_lds[w][n][s][t] * qkv_lds[w][t][128 + lane];
                o_lds[w][s][lane] = acc;
            }
        }
        __syncthreads();

        // ---- out proj + residual ----
        {
            const float* Wo = out_w + (size_t)l * 64 * 64;
            float acc[SEQ];
#pragma unroll
            for (int s = 0; s < SEQ; ++s) acc[s] = 0.f;
#pragma unroll 4
            for (int j = 0; j < 64; ++j) {
                float wvv = Wo[j * 64 + lane];
#pragma unroll
                for (int s = 0; s < SEQ; ++s) acc[s] += o_lds[w][s][j] * wvv;
            }
            float bias = out_b[l * 64 + lane];
#pragma unroll
            for (int s = 0; s < SEQ; ++s) x[s] += acc[s] + bias;
        }
        __syncthreads();

        // ---- LN2 ----
        {
            float g = ln2_g[l * 64 + lane], bb = ln2_b[l * 64 + lane];
#pragma unroll
            for (int s = 0; s < SEQ; ++s) {
                float val = x[s];
                float m   = wred(val) * (1.f / 64.f);
                float dv  = val - m;
                float var = wred(dv * dv) * (1.f / 64.f);
                h_lds[w][s][lane] = dv * rsqrtf(var + 1e-5f) * g + bb;
            }
        }
        __syncthreads();

        // ---- MLP1 + exact GELU ----
        {
            const float* W1 = mlp_w1 + (size_t)l * 64 * 128;
#pragma unroll
            for (int c = 0; c < 2; ++c) {
                float acc[SEQ];
#pragma unroll
                for (int s = 0; s < SEQ; ++s) acc[s] = 0.f;
#pragma unroll 4
                for (int d = 0; d < 64; ++d) {
                    float wvv = W1[d * 128 + c * 64 + lane];
#pragma unroll
                    for (int s = 0; s < SEQ; ++s) acc[s] += h_lds[w][s][d] * wvv;
                }
                float bias = mlp_b1[l * 128 + c * 64 + lane];
#pragma unroll
                for (int s = 0; s < SEQ; ++s) {
                    float u = acc[s] + bias;
                    m_lds[w][s][c * 64 + lane] = 0.5f * u * (1.f + erff(u * 0.70710678118654752f));
                }
            }
        }
        __syncthreads();

        // ---- MLP2 + residual ----
        {
            const float* W2 = mlp_w2 + (size_t)l * 128 * 64;
            float acc[SEQ];
#pragma unroll
            for (int s = 0; s < SEQ; ++s) acc[s] = 0.f;
#pragma unroll 4
            for (int j = 0; j < 128; ++j) {
                float wvv = W2[j * 64 + lane];
#pragma unroll
                for (int s = 0; s < SEQ; ++s) acc[s] += m_lds[w][s][j] * wvv;
            }
            float bias = mlp_b2[l * 64 + lane];
#pragma unroll
            for (int s = 0; s < SEQ; ++s) x[s] += acc[s] + bias;
        }
        __syncthreads();
    }

    // ---- head: LN(cls) @ head_w -> softmax(2) ----
    {
        float val = x[0];
        float m   = wred(val) * (1.f / 64.f);
        float dv  = val - m;
        float var = wred(dv * dv) * (1.f / 64.f);
        float hh  = dv * rsqrtf(var + 1e-5f) * head_g[lane] + head_b[lane];
        float l0  = wred(hh * head_w[lane * 2 + 0]);
        float l1  = wred(hh * head_w[lane * 2 + 1]);
        if (lane == 0) {
            l0 += head_bias[0];
            l1 += head_bias[1];
            float mx = fmaxf(l0, l1);
            float e0 = __expf(l0 - mx), e1 = __expf(l1 - mx);
            float inv = 1.f / (e0 + e1);
            out[(size_t)b * 2 + 0] = e0 * inv;
            out[(size_t)b * 2 + 1] = e1 * inv;
        }
    }
}

// ---------------- launch ----------------
extern "C" void kernel_launch(void* const* d_in, const int* in_sizes, int n_in,
                              void* d_out, int out_size, void* d_ws, size_t ws_size,
                              hipStream_t stream) {
    const float* xin     = (const float*)d_in[0];
    const float* proj_w  = (const float*)d_in[1];
    const float* proj_b  = (const float*)d_in[2];
    const float* cls     = (const float*)d_in[3];
    const float* pe      = (const float*)d_in[4];
    const float* qkv_w   = (const float*)d_in[5];
    const float* qkv_b   = (const float*)d_in[6];
    const float* out_w   = (const float*)d_in[7];
    const float* out_b   = (const float*)d_in[8];
    const float* ln1_g   = (const float*)d_in[9];
    const float* ln1_b   = (const float*)d_in[10];
    const float* ln2_g   = (const float*)d_in[11];
    const float* ln2_b   = (const float*)d_in[12];
    const float* mlp_w1  = (const float*)d_in[13];
    const float* mlp_b1  = (const float*)d_in[14];
    const float* mlp_w2  = (const float*)d_in[15];
    const float* mlp_b2  = (const float*)d_in[16];
    const float* head_g  = (const float*)d_in[17];
    const float* head_b  = (const float*)d_in[18];
    const float* head_w  = (const float*)d_in[19];
    const float* head_bs = (const float*)d_in[20];
    float* outp = (float*)d_out;

    float* x0 = (float*)d_ws;  // B*6*64 floats = 25.2 MB

    proj_kernel<<<PROJ_BLOCKS + 16, 256, 0, stream>>>(
        xin, proj_w, proj_b, cls, pe, x0);

    tf_kernel<<<B_TOT / SMP_TF, 256, 0, stream>>>(
        x0, qkv_w, qkv_b, out_w, out_b, ln1_g, ln1_b, ln2_g, ln2_b,
        mlp_w1, mlp_b1, mlp_w2, mlp_b2, head_g, head_b, head_w, head_bs, outp);
}

// Round 6
// 1359.713 us; speedup vs baseline: 1.7697x; 1.5751x over previous
//
#include <hip/hip_runtime.h>
#include <hip/hip_bf16.h>
#include <math.h>

// ---------------------------------------------------------------------------
// EEG-ViT forward. Round 6 (re-land of round-5 MFMA rewrite; broker timeout).
// proj_kernel: round-4 version (824 us, bit-exact), epilogue junk removed.
// prep_kernel: transpose+bf16-hi/lo-split all transformer weights into d_ws
//   as B_ext[n][k_ext] with k-sections [wh | wh | wl] (pairs with A=[xh|xl|xh]).
// tf2_kernel: 6 layers via mfma_f32_16x16x32_bf16 with hi/lo extended-K
//   emulation (~fp32 accurate). Block = 8 samples = 48 rows = 3 M-tiles.
//   Residual x / h / qkv / m panels in LDS (81,408 B -> 2 blocks/CU).
//   LN + attention + GELU in fp32 on VALU. 8 barriers/layer.
// ---------------------------------------------------------------------------

#define B_TOT   16384
#define SEQ     6
#define NLAYER  6

typedef float f4 __attribute__((ext_vector_type(4)));
typedef float v4f __attribute__((ext_vector_type(4)));
typedef __bf16 v8bf __attribute__((ext_vector_type(8)));
typedef unsigned short us16;

// ---------------- Kernel 1: projection (validated round-4) ----------------
#define PROJ_BLOCKS 640
#define ROWS_BLK    128
#define XSTR        28

__global__ __launch_bounds__(256) void proj_kernel(
    const float* __restrict__ xin, const float* __restrict__ Wp,
    const float* __restrict__ pb, const float* __restrict__ cls,
    const float* __restrict__ pe, float* __restrict__ x0)
{
    const int tid  = threadIdx.x;
    const int blk  = blockIdx.x;

    if (blk >= PROJ_BLOCKS) {
        const float pe0 = pe[0];
        const f4* cls4 = (const f4*)cls;
        f4 cv[16];
#pragma unroll
        for (int j = 0; j < 16; ++j) cv[j] = cls4[j] + pe0;
        int r0 = (blk - PROJ_BLOCKS) * 1024 + tid * 4;
#pragma unroll
        for (int rr = 0; rr < 4; ++rr) {
            f4* dst = (f4*)(x0 + (size_t)(r0 + rr) * 384);
#pragma unroll
            for (int j = 0; j < 16; ++j) dst[j] = cv[j];
        }
        return;
    }

    __shared__ float xlds[2][ROWS_BLK * XSTR];
    __shared__ float wlds[2][25 * 64];

    const int lane = tid & 63;
    const int wv   = tid >> 6;
    const int rg   = lane >> 3;
    const int cg   = lane & 7;
    const int brow0 = blk * ROWS_BLK;

    unsigned goff[13];
    unsigned loff[13];
#pragma unroll
    for (int j = 0; j < 13; ++j) {
        int flat = tid + j * 256;
        if (j < 12 || tid < 128) {
            int row  = flat / 25;
            int t    = flat - row * 25;
            int grow = brow0 + row;
            int smp  = grow / 5;
            int p    = grow - smp * 5;
            goff[j] = (unsigned)smp * 8000u + (unsigned)p * 25u + (unsigned)t;
            loff[j] = (unsigned)(row * XSTR + t);
        } else { goff[j] = 0u; loff[j] = 0u; }
    }

    const f4* Wp4 = (const f4*)Wp;

    f4 acc[4][2];
#pragma unroll
    for (int j = 0; j < 4; ++j) { acc[j][0] = (f4)0.f; acc[j][1] = (f4)0.f; }

    float xg[13];
    f4    wg[2];

    {
#pragma unroll
        for (int j = 0; j < 12; ++j) xg[j] = xin[goff[j]];
        if (tid < 128) xg[12] = xin[goff[12]];
        wg[0] = Wp4[tid];
        if (tid < 144) wg[1] = Wp4[256 + tid];
#pragma unroll
        for (int j = 0; j < 12; ++j) xlds[0][loff[j]] = xg[j];
        if (tid < 128) xlds[0][loff[12]] = xg[12];
        ((f4*)wlds[0])[tid] = wg[0];
        if (tid < 144) ((f4*)wlds[0])[256 + tid] = wg[1];
    }
    __syncthreads();

    const int xbase = (wv * 32 + rg * 4) * XSTR;
    const int wcol  = cg * 8;

    for (int h = 0; h < 64; ++h) {
        const int bb = h & 1;
        if (h < 63) {
            const unsigned gadd = (unsigned)(h + 1) * 125u;
#pragma unroll
            for (int j = 0; j < 12; ++j) xg[j] = xin[goff[j] + gadd];
            if (tid < 128) xg[12] = xin[goff[12] + gadd];
            const f4* wsrc = Wp4 + (size_t)(h + 1) * 400;
            wg[0] = wsrc[tid];
            if (tid < 144) wg[1] = wsrc[256 + tid];
        }
        {
            const float* xw = &xlds[bb][xbase];
            const float* wb = &wlds[bb][wcol];
#pragma unroll
            for (int t4 = 0; t4 < 6; ++t4) {
                f4 xr[4];
#pragma unroll
                for (int j = 0; j < 4; ++j)
                    xr[j] = *(const f4*)&xw[j * XSTR + t4 * 4];
#pragma unroll
                for (int kk = 0; kk < 4; ++kk) {
                    const float* wrow = &wb[(t4 * 4 + kk) * 64];
                    f4 wa = *(const f4*)&wrow[0];
                    f4 wc = *(const f4*)&wrow[4];
#pragma unroll
                    for (int j = 0; j < 4; ++j) {
                        float xv = xr[j][kk];
                        acc[j][0] += xv * wa;
                        acc[j][1] += xv * wc;
                    }
                }
            }
            {
                const float* wrow = &wb[24 * 64];
                f4 wa = *(const f4*)&wrow[0];
                f4 wc = *(const f4*)&wrow[4];
#pragma unroll
                for (int j = 0; j < 4; ++j) {
                    float xv = xw[j * XSTR + 24];
                    acc[j][0] += xv * wa;
                    acc[j][1] += xv * wc;
                }
            }
        }
        if (h < 63) {
            const int nb = bb ^ 1;
#pragma unroll
            for (int j = 0; j < 12; ++j) xlds[nb][loff[j]] = xg[j];
            if (tid < 128) xlds[nb][loff[12]] = xg[12];
            ((f4*)wlds[nb])[tid] = wg[0];
            if (tid < 144) ((f4*)wlds[nb])[256 + tid] = wg[1];
        }
        __syncthreads();
    }

    // ---- epilogue: bias + pe, store (clean r4 form) ----
    const f4* pb4 = (const f4*)pb;
    const f4 pbv0 = pb4[cg * 2], pbv1 = pb4[cg * 2 + 1];
    const float peP[5] = {pe[1], pe[2], pe[3], pe[4], pe[5]};
#pragma unroll
    for (int j = 0; j < 4; ++j) {
        int grow = brow0 + wv * 32 + rg * 4 + j;
        int smp  = grow / 5;
        int p    = grow - smp * 5;
        float pev = peP[p];
        float* dst = x0 + ((size_t)smp * SEQ + (p + 1)) * 64 + cg * 8;
        *(f4*)dst       = acc[j][0] + pbv0 + pev;
        *(f4*)(dst + 4) = acc[j][1] + pbv1 + pev;
    }
}

// ---------------- Kernel 1.5: weight prep (transpose + hi/lo split) -------
// Layout per layer (98304 us16): Wq_t[192][192] @0, Wo_t[64][192] @36864,
// W1_t[128][192] @49152, W2_t[64][384] @73728. k-sections: [wh | wh | wl].
#define PREP_TOT (6 * 98304)

__global__ __launch_bounds__(256) void prep_kernel(
    const float* __restrict__ qkv_w, const float* __restrict__ out_w,
    const float* __restrict__ mlp_w1, const float* __restrict__ mlp_w2,
    us16* __restrict__ Wext)
{
    int gid = blockIdx.x * 256 + threadIdx.x;
    if (gid >= PREP_TOT) return;
    int l = gid / 98304;
    int r = gid - l * 98304;
    int sec; float v;
    if (r < 36864) {
        int n = r / 192, k = r - n * 192; sec = k >> 6; int ks = k & 63;
        v = qkv_w[(size_t)(l * 64 + ks) * 192 + n];
    } else if (r < 49152) {
        int r2 = r - 36864; int n = r2 / 192, k = r2 - n * 192; sec = k >> 6; int ks = k & 63;
        v = out_w[(size_t)(l * 64 + ks) * 64 + n];
    } else if (r < 73728) {
        int r3 = r - 49152; int n = r3 / 192, k = r3 - n * 192; sec = k >> 6; int ks = k & 63;
        v = mlp_w1[(size_t)(l * 64 + ks) * 128 + n];
    } else {
        int r4 = r - 73728; int n = r4 / 384, k = r4 - n * 384; sec = k >> 7; int ks = k & 127;
        v = mlp_w2[(size_t)(l * 128 + ks) * 64 + n];
    }
    __bf16 hb = (__bf16)v;
    us16 u;
    if (sec < 2) u = __builtin_bit_cast(us16, hb);
    else {
        float rem = v - (float)hb;
        __bf16 lb = (__bf16)rem;
        u = __builtin_bit_cast(us16, lb);
    }
    Wext[gid] = u;
}

// ---------------- Kernel 2: MFMA transformer ----------------
#define XS 68     // x panel stride (f32)
#define HS 136    // h/o panel stride (bf16): [xh 64 | xl 64] + pad, chunk-XOR swizzled
#define QS 196    // qkv panel stride (f32)
#define MS 264    // m panel stride (bf16): [mh 128 | ml 128] + pad, swizzled

__device__ __forceinline__ float wred64(float v) {
#pragma unroll
    for (int o = 32; o > 0; o >>= 1) v += __shfl_xor(v, o, 64);
    return v;
}

__device__ __forceinline__ us16 bf_hi(float v) {
    __bf16 h = (__bf16)v; return __builtin_bit_cast(us16, h);
}
__device__ __forceinline__ us16 bf_lo(float v) {
    __bf16 h = (__bf16)v;
    float rem = v - (float)h;
    __bf16 l = (__bf16)rem;
    return __builtin_bit_cast(us16, l);
}

// A-fragment loader from a hi/lo 64-col panel (KE=192 mapping).
// kt 0,1 -> xh ; kt 2,3 -> xl ; kt 4,5 -> xh   (pairs B [wh|wh|wl])
__device__ __forceinline__ void load_a_ke1(const us16* hp, int lane, v8bf a[3][6]) {
    const int g = lane >> 4;
#pragma unroll
    for (int mt = 0; mt < 3; ++mt) {
        int r  = mt * 16 + (lane & 15);
        int rx = r & 7;
        int rb = r * HS;
#pragma unroll
        for (int kt = 0; kt < 6; ++kt) {
            int sec = ((kt >> 1) == 1) ? 1 : 0;
            int c3  = ((kt & 1) << 2) + g;
            a[mt][kt] = *(const v8bf*)&hp[rb + sec * 64 + ((c3 ^ rx) << 3)];
        }
    }
}

// LN over x panel rows -> hi/lo bf16 panel (swizzled). Wave w owns rows 12w..12w+11.
__device__ __forceinline__ void ln_to_panel(const float* xp, us16* hp,
                                            const float* g_, const float* b_,
                                            int lane, int w) {
    f4 g4 = *(const f4*)&g_[(lane & 15) * 4];
    f4 b4 = *(const f4*)&b_[(lane & 15) * 4];
#pragma unroll
    for (int it = 0; it < 3; ++it) {
        int r = w * 12 + it * 4 + (lane >> 4);
        f4 xv = *(const f4*)&xp[r * XS + (lane & 15) * 4];
        float s = xv[0] + xv[1] + xv[2] + xv[3];
        s += __shfl_xor(s, 1, 64); s += __shfl_xor(s, 2, 64);
        s += __shfl_xor(s, 4, 64); s += __shfl_xor(s, 8, 64);
        float mean = s * (1.f / 64.f);
        f4 dv = xv - mean;
        float vs = dv[0]*dv[0] + dv[1]*dv[1] + dv[2]*dv[2] + dv[3]*dv[3];
        vs += __shfl_xor(vs, 1, 64); vs += __shfl_xor(vs, 2, 64);
        vs += __shfl_xor(vs, 4, 64); vs += __shfl_xor(vs, 8, 64);
        float rs = rsqrtf(vs * (1.f / 64.f) + 1e-5f);
        f4 h4 = dv * rs * g4 + b4;
        int C0 = (lane & 15) * 4;
        int chunk = C0 >> 3, e = C0 & 7;
        int ad = r * HS + ((chunk ^ (r & 7)) << 3) + e;
        ushort4 hi, lo;
        hi.x = bf_hi(h4[0]); hi.y = bf_hi(h4[1]); hi.z = bf_hi(h4[2]); hi.w = bf_hi(h4[3]);
        lo.x = bf_lo(h4[0]); lo.y = bf_lo(h4[1]); lo.z = bf_lo(h4[2]); lo.w = bf_lo(h4[3]);
        *(ushort4*)&hp[ad]      = hi;
        *(ushort4*)&hp[ad + 64] = lo;
    }
}

__global__ __launch_bounds__(256, 2) void tf2_kernel(
    const float* __restrict__ x0buf,
    const us16*  __restrict__ Wext,
    const float* __restrict__ qkv_b, const float* __restrict__ out_b,
    const float* __restrict__ ln1_g, const float* __restrict__ ln1_b,
    const float* __restrict__ ln2_g, const float* __restrict__ ln2_b,
    const float* __restrict__ mlp_b1, const float* __restrict__ mlp_b2,
    const float* __restrict__ head_g, const float* __restrict__ head_b,
    const float* __restrict__ head_w, const float* __restrict__ head_bias,
    float* __restrict__ out)
{
    __shared__ __align__(16) float x_lds[48 * XS];            // 13056 B
    __shared__ __align__(16) us16  h_lds[48 * HS];            // 13056 B
    __shared__ __align__(16) unsigned char u_buf[48 * MS * 2];// 50688 B (qkv f32 / m bf16)
    __shared__ __align__(16) float att_lds[8 * 4 * 36];       // 4608 B

    float* qkv_lds = (float*)u_buf;
    us16*  m_lds   = (us16*)u_buf;

    const int tid  = threadIdx.x;
    const int lane = tid & 63;
    const int w    = tid >> 6;
    const int bid  = blockIdx.x;

    // ---- load x panel ----
#pragma unroll
    for (int j = 0; j < 3; ++j) {
        int idx = tid + j * 256;          // 0..767 over 48 rows x 16 f4
        int row = idx >> 4, c4 = idx & 15;
        *(f4*)&x_lds[row * XS + c4 * 4] =
            *(const f4*)&x0buf[((size_t)bid * 48 + row) * 64 + c4 * 4];
    }
    __syncthreads();

    for (int lay = 0; lay < NLAYER; ++lay) {
        const int lb = lay * 98304;

        // ---- P0: LN1 -> h panel ----
        ln_to_panel(x_lds, h_lds, ln1_g + lay * 64, ln1_b + lay * 64, lane, w);
        __syncthreads();

        // ---- P1: QKV GEMM (N=192, wave w -> nt {3w..3w+2}) ----
        {
            v8bf a[3][6];
            load_a_ke1(h_lds, lane, a);
            const us16* Bq = Wext + lb;
            const float* qb = qkv_b + lay * 192;
            const int g = lane >> 4;
#pragma unroll
            for (int ntl = 0; ntl < 3; ++ntl) {
                int nt = w * 3 + ntl;
                int C  = nt * 16 + (lane & 15);
                v4f acc0 = {0.f,0.f,0.f,0.f}, acc1 = acc0, acc2 = acc0;
#pragma unroll
                for (int kt = 0; kt < 6; ++kt) {
                    v8bf b = *(const v8bf*)&Bq[C * 192 + kt * 32 + g * 8];
                    acc0 = __builtin_amdgcn_mfma_f32_16x16x32_bf16(a[0][kt], b, acc0, 0, 0, 0);
                    acc1 = __builtin_amdgcn_mfma_f32_16x16x32_bf16(a[1][kt], b, acc1, 0, 0, 0);
                    acc2 = __builtin_amdgcn_mfma_f32_16x16x32_bf16(a[2][kt], b, acc2, 0, 0, 0);
                }
                float bias = qb[C];
#pragma unroll
                for (int reg = 0; reg < 4; ++reg) {
                    int rr = g * 4 + reg;
                    qkv_lds[(0 * 16 + rr) * QS + C]  = acc0[reg] + bias;
                    qkv_lds[(1 * 16 + rr) * QS + C]  = acc1[reg] + bias;
                    qkv_lds[(2 * 16 + rr) * QS + C]  = acc2[reg] + bias;
                }
            }
        }
        __syncthreads();

        // ---- P2: scores + softmax (192 tasks: sample, head, row) ----
        if (tid < 192) {
            int a8 = tid / 24, rem = tid - a8 * 24;
            int hh = rem / 6, i = rem - hh * 6;
            int rb = a8 * 6;
            const float* qrow = &qkv_lds[(rb + i) * QS + hh * 16];
            f4 q0 = *(const f4*)&qrow[0],  q1 = *(const f4*)&qrow[4];
            f4 q2 = *(const f4*)&qrow[8],  q3 = *(const f4*)&qrow[12];
            float sc[6];
#pragma unroll
            for (int j = 0; j < 6; ++j) {
                const float* kr = &qkv_lds[(rb + j) * QS + 64 + hh * 16];
                f4 k0 = *(const f4*)&kr[0], k1 = *(const f4*)&kr[4];
                f4 k2 = *(const f4*)&kr[8], k3 = *(const f4*)&kr[12];
                f4 p = q0 * k0 + q1 * k1 + q2 * k2 + q3 * k3;
                sc[j] = (p[0] + p[1] + p[2] + p[3]) * 0.25f;
            }
            float mx = sc[0];
#pragma unroll
            for (int j = 1; j < 6; ++j) mx = fmaxf(mx, sc[j]);
            float e[6], sum = 0.f;
#pragma unroll
            for (int j = 0; j < 6; ++j) { e[j] = expf(sc[j] - mx); sum += e[j]; }
            float inv = 1.f / sum;
            float* ap = &att_lds[((a8 * 4 + hh) * 6 + i) * 6];
#pragma unroll
            for (int j = 0; j < 6; ++j) ap[j] = e[j] * inv;
        }
        __syncthreads();

        // ---- P3: PV -> o panel (hi/lo, swizzled, over h_lds) ----
        {
            int cg = tid & 15, rgrp = tid >> 4;
            int hh = cg >> 2;
#pragma unroll
            for (int k = 0; k < 3; ++k) {
                int r = rgrp + 16 * k;
                int a8 = r / 6, i = r - a8 * 6;
                int rb = a8 * 6;
                const float* ap = &att_lds[((a8 * 4 + hh) * 6 + i) * 6];
                f4 o = {0.f,0.f,0.f,0.f};
#pragma unroll
                for (int j = 0; j < 6; ++j)
                    o += ap[j] * *(const f4*)&qkv_lds[(rb + j) * QS + 128 + cg * 4];
                int C0 = cg * 4;
                int chunk = C0 >> 3, e = C0 & 7;
                int ad = r * HS + ((chunk ^ (r & 7)) << 3) + e;
                ushort4 hi, lo;
                hi.x = bf_hi(o[0]); hi.y = bf_hi(o[1]); hi.z = bf_hi(o[2]); hi.w = bf_hi(o[3]);
                lo.x = bf_lo(o[0]); lo.y = bf_lo(o[1]); lo.z = bf_lo(o[2]); lo.w = bf_lo(o[3]);
                *(ushort4*)&h_lds[ad]      = hi;
                *(ushort4*)&h_lds[ad + 64] = lo;
            }
        }
        __syncthreads();

        // ---- P4: out-proj GEMM (N=64, wave w -> nt w) + residual ----
        {
            v8bf a[3][6];
            load_a_ke1(h_lds, lane, a);
            const us16* Bo = Wext + lb + 36864;
            const int g = lane >> 4;
            int C = w * 16 + (lane & 15);
            v4f acc0 = {0.f,0.f,0.f,0.f}, acc1 = acc0, acc2 = acc0;
#pragma unroll
            for (int kt = 0; kt < 6; ++kt) {
                v8bf b = *(const v8bf*)&Bo[C * 192 + kt * 32 + g * 8];
                acc0 = __builtin_amdgcn_mfma_f32_16x16x32_bf16(a[0][kt], b, acc0, 0, 0, 0);
                acc1 = __builtin_amdgcn_mfma_f32_16x16x32_bf16(a[1][kt], b, acc1, 0, 0, 0);
                acc2 = __builtin_amdgcn_mfma_f32_16x16x32_bf16(a[2][kt], b, acc2, 0, 0, 0);
            }
            float bias = out_b[lay * 64 + C];
#pragma unroll
            for (int reg = 0; reg < 4; ++reg) {
                int rr = g * 4 + reg;
                x_lds[(0 * 16 + rr) * XS + C] += acc0[reg] + bias;
                x_lds[(1 * 16 + rr) * XS + C] += acc1[reg] + bias;
                x_lds[(2 * 16 + rr) * XS + C] += acc2[reg] + bias;
            }
        }
        __syncthreads();

        // ---- P5: LN2 -> h panel ----
        ln_to_panel(x_lds, h_lds, ln2_g + lay * 64, ln2_b + lay * 64, lane, w);
        __syncthreads();

        // ---- P6: MLP1 GEMM (N=128, wave w -> nt {2w,2w+1}) + GELU -> m ----
        {
            v8bf a[3][6];
            load_a_ke1(h_lds, lane, a);
            const us16* B1 = Wext + lb + 49152;
            const float* b1 = mlp_b1 + lay * 128;
            const int g = lane >> 4;
#pragma unroll
            for (int q = 0; q < 2; ++q) {
                int nt = w * 2 + q;
                int C  = nt * 16 + (lane & 15);
                v4f acc0 = {0.f,0.f,0.f,0.f}, acc1 = acc0, acc2 = acc0;
#pragma unroll
                for (int kt = 0; kt < 6; ++kt) {
                    v8bf b = *(const v8bf*)&B1[C * 192 + kt * 32 + g * 8];
                    acc0 = __builtin_amdgcn_mfma_f32_16x16x32_bf16(a[0][kt], b, acc0, 0, 0, 0);
                    acc1 = __builtin_amdgcn_mfma_f32_16x16x32_bf16(a[1][kt], b, acc1, 0, 0, 0);
                    acc2 = __builtin_amdgcn_mfma_f32_16x16x32_bf16(a[2][kt], b, acc2, 0, 0, 0);
                }
                float bias = b1[C];
                int ch4 = C >> 3, e = C & 7;
#pragma unroll
                for (int mt = 0; mt < 3; ++mt) {
                    v4f acc = (mt == 0) ? acc0 : ((mt == 1) ? acc1 : acc2);
#pragma unroll
                    for (int reg = 0; reg < 4; ++reg) {
                        int row = mt * 16 + g * 4 + reg;
                        float u = acc[reg] + bias;
                        float gl = 0.5f * u * (1.f + erff(u * 0.70710678118654752f));
                        int ad = row * MS + ((ch4 ^ (row & 7)) << 3) + e;
                        m_lds[ad]       = bf_hi(gl);
                        m_lds[ad + 128] = bf_lo(gl);
                    }
                }
            }
        }
        __syncthreads();

        // ---- P7: MLP2 GEMM (K=128 -> KE=384, N=64, wave w -> nt w) + residual ----
        {
            v8bf a[3][12];
            const int g = lane >> 4;
#pragma unroll
            for (int mt = 0; mt < 3; ++mt) {
                int r  = mt * 16 + (lane & 15);
                int rx = r & 7;
                int rb = r * MS;
#pragma unroll
                for (int kt = 0; kt < 12; ++kt) {
                    int sec = (kt >> 2);                  // 0: mh  1: ml  2: mh
                    int off = (sec == 1) ? 128 : 0;
                    int c4  = ((kt & 3) << 2) + g;
                    a[mt][kt] = *(const v8bf*)&m_lds[rb + off + ((c4 ^ rx) << 3)];
                }
            }
            const us16* B2 = Wext + lb + 73728;
            int C = w * 16 + (lane & 15);
            v4f acc0 = {0.f,0.f,0.f,0.f}, acc1 = acc0, acc2 = acc0;
#pragma unroll
            for (int kt = 0; kt < 12; ++kt) {
                v8bf b = *(const v8bf*)&B2[C * 384 + kt * 32 + g * 8];
                acc0 = __builtin_amdgcn_mfma_f32_16x16x32_bf16(a[0][kt], b, acc0, 0, 0, 0);
                acc1 = __builtin_amdgcn_mfma_f32_16x16x32_bf16(a[1][kt], b, acc1, 0, 0, 0);
                acc2 = __builtin_amdgcn_mfma_f32_16x16x32_bf16(a[2][kt], b, acc2, 0, 0, 0);
            }
            float bias = mlp_b2[lay * 64 + C];
#pragma unroll
            for (int reg = 0; reg < 4; ++reg) {
                int rr = g * 4 + reg;
                x_lds[(0 * 16 + rr) * XS + C] += acc0[reg] + bias;
                x_lds[(1 * 16 + rr) * XS + C] += acc1[reg] + bias;
                x_lds[(2 * 16 + rr) * XS + C] += acc2[reg] + bias;
            }
        }
        __syncthreads();
    }

    // ---- head: LN(cls rows) -> 2-class softmax ----
#pragma unroll
    for (int si = 0; si < 2; ++si) {
        int s = w * 2 + si;
        float val = x_lds[(s * 6) * XS + lane];
        float m  = wred64(val) * (1.f / 64.f);
        float dv = val - m;
        float var = wred64(dv * dv) * (1.f / 64.f);
        float hh  = dv * rsqrtf(var + 1e-5f) * head_g[lane] + head_b[lane];
        float l0  = wred64(hh * head_w[lane * 2 + 0]);
        float l1  = wred64(hh * head_w[lane * 2 + 1]);
        if (lane == 0) {
            l0 += head_bias[0];
            l1 += head_bias[1];
            float mx = fmaxf(l0, l1);
            float e0 = expf(l0 - mx), e1 = expf(l1 - mx);
            float inv = 1.f / (e0 + e1);
            out[(size_t)(bid * 8 + s) * 2 + 0] = e0 * inv;
            out[(size_t)(bid * 8 + s) * 2 + 1] = e1 * inv;
        }
    }
}

// ---------------- launch ----------------
extern "C" void kernel_launch(void* const* d_in, const int* in_sizes, int n_in,
                              void* d_out, int out_size, void* d_ws, size_t ws_size,
                              hipStream_t stream) {
    const float* xin     = (const float*)d_in[0];
    const float* proj_w  = (const float*)d_in[1];
    const float* proj_b  = (const float*)d_in[2];
    const float* cls     = (const float*)d_in[3];
    const float* pe      = (const float*)d_in[4];
    const float* qkv_w   = (const float*)d_in[5];
    const float* qkv_b   = (const float*)d_in[6];
    const float* out_w   = (const float*)d_in[7];
    const float* out_b   = (const float*)d_in[8];
    const float* ln1_g   = (const float*)d_in[9];
    const float* ln1_b   = (const float*)d_in[10];
    const float* ln2_g   = (const float*)d_in[11];
    const float* ln2_b   = (const float*)d_in[12];
    const float* mlp_w1  = (const float*)d_in[13];
    const float* mlp_b1  = (const float*)d_in[14];
    const float* mlp_w2  = (const float*)d_in[15];
    const float* mlp_b2  = (const float*)d_in[16];
    const float* head_g  = (const float*)d_in[17];
    const float* head_b  = (const float*)d_in[18];
    const float* head_w  = (const float*)d_in[19];
    const float* head_bs = (const float*)d_in[20];
    float* outp = (float*)d_out;

    float* x0   = (float*)d_ws;                               // 25,165,824 B
    us16*  Wext = (us16*)((char*)d_ws + 25165824);            // 1,179,648 B

    prep_kernel<<<(PREP_TOT + 255) / 256, 256, 0, stream>>>(
        qkv_w, out_w, mlp_w1, mlp_w2, Wext);

    proj_kernel<<<PROJ_BLOCKS + 16, 256, 0, stream>>>(
        xin, proj_w, proj_b, cls, pe, x0);

    tf2_kernel<<<B_TOT / 8, 256, 0, stream>>>(
        x0, Wext, qkv_b, out_b, ln1_g, ln1_b, ln2_g, ln2_b,
        mlp_b1, mlp_b2, head_g, head_b, head_w, head_bs, outp);
}

// Round 7
// 1221.684 us; speedup vs baseline: 1.9696x; 1.1130x over previous
//
#include <hip/hip_runtime.h>
#include <hip/hip_bf16.h>
#include <math.h>

// ---------------------------------------------------------------------------
// EEG-ViT forward. Round 7.
// proj2_kernel: MFMA patchify+projection. Block = 64 patch-rows; per h-step
//   stage x as hi/lo bf16 [64][64] XOR-swizzled LDS panel (ds_write_b64 in,
//   conflict-free ds_read_b128 out), weights pre-split to Wpx[n][h][3][32]
//   (L2-resident, B-frags straight from global). Wave = 1 n-tile x 4 m-tiles.
//   Extended-K hi/lo: A=[xh|xl|xh] . B=[wh|wh|wl]  (~fp32 accuracy).
// prep_kernel: tf weights (unchanged layout) + proj weight split.
// tf2_kernel: UNCHANGED validated round-6 MFMA transformer.
// ---------------------------------------------------------------------------

#define B_TOT   16384
#define SEQ     6
#define NLAYER  6

typedef float f4 __attribute__((ext_vector_type(4)));
typedef float v4f __attribute__((ext_vector_type(4)));
typedef __bf16 v8bf __attribute__((ext_vector_type(8)));
typedef unsigned short us16;

__device__ __forceinline__ us16 bf_hi(float v) {
    __bf16 h = (__bf16)v; return __builtin_bit_cast(us16, h);
}
__device__ __forceinline__ us16 bf_lo(float v) {
    __bf16 h = (__bf16)v;
    float rem = v - (float)h;
    __bf16 l = (__bf16)rem;
    return __builtin_bit_cast(us16, l);
}

// ---------------- Kernel 1: MFMA projection ----------------
#define PB2 1280   // 64 rows per block

__global__ __launch_bounds__(256) void proj2_kernel(
    const float* __restrict__ xin,   // (B, 8000)
    const us16*  __restrict__ Wpx,   // (64 n, 64 h, 3 sec, 32 k)
    const float* __restrict__ pb,    // (64)
    const float* __restrict__ cls,   // (64)
    const float* __restrict__ pe,    // (6)
    float* __restrict__ x0)          // (B, 6, 64)
{
    const int tid = threadIdx.x;
    const int blk = blockIdx.x;

    if (blk >= PB2) {
        // ---- cls rows ----
        const float pe0 = pe[0];
        const f4* cls4 = (const f4*)cls;
        f4 cv[16];
#pragma unroll
        for (int j = 0; j < 16; ++j) cv[j] = cls4[j] + pe0;
        int r0 = (blk - PB2) * 1024 + tid * 4;
#pragma unroll
        for (int rr = 0; rr < 4; ++rr) {
            f4* dst = (f4*)(x0 + (size_t)(r0 + rr) * 384);
#pragma unroll
            for (int j = 0; j < 16; ++j) dst[j] = cv[j];
        }
        return;
    }

    __shared__ __align__(16) us16 xpan[2][64 * 64];   // 2 x 8 KB

    const int lane = tid & 63;
    const int w    = tid >> 6;        // wave = n-tile
    const int c    = lane & 15;
    const int g    = lane >> 4;
    const int brow0 = blk * 64;

    // ---- staging precompute: 2 quad-groups per thread ----
    // group idx (0..511): row = idx>>3, q = idx&7, covers t = q*4 .. q*4+3 (t<25 real)
    unsigned gb[2];      // global float offset excl h*125
    int      q_[2];
    unsigned ahi[2], alo[2];
#pragma unroll
    for (int j = 0; j < 2; ++j) {
        int idx = tid + j * 256;
        int row = idx >> 3, q = idx & 7;
        int grow = brow0 + row;
        int smp = grow / 5;
        int p   = grow - smp * 5;
        gb[j] = (unsigned)smp * 8000u + (unsigned)p * 25u + (unsigned)(q * 4);
        q_[j] = q;
        int ch_hi = q >> 1;
        int ch_lo = (q >> 1) + 4;
        ahi[j] = (unsigned)(row * 64 + (((ch_hi ^ (row & 7))) << 3) + (q & 1) * 4);
        alo[j] = (unsigned)(row * 64 + (((ch_lo ^ (row & 7))) << 3) + (q & 1) * 4);
    }

    v4f acc[4];
#pragma unroll
    for (int mt = 0; mt < 4; ++mt) acc[mt] = (v4f){0.f, 0.f, 0.f, 0.f};

    // ---- prologue: stage h=0 ----
    {
#pragma unroll
        for (int j = 0; j < 2; ++j) {
            float v[4];
#pragma unroll
            for (int e = 0; e < 4; ++e) {
                int t = q_[j] * 4 + e;
                v[e] = (t < 25) ? xin[gb[j] + e] : 0.f;
            }
            ushort4 hv, lv;
            hv.x = bf_hi(v[0]); hv.y = bf_hi(v[1]); hv.z = bf_hi(v[2]); hv.w = bf_hi(v[3]);
            lv.x = bf_lo(v[0]); lv.y = bf_lo(v[1]); lv.z = bf_lo(v[2]); lv.w = bf_lo(v[3]);
            *(ushort4*)&xpan[0][ahi[j]] = hv;
            *(ushort4*)&xpan[0][alo[j]] = lv;
        }
    }
    __syncthreads();

    const us16* Bn = Wpx + (size_t)(w * 16 + c) * 6144;   // [h][3][32]
    const int achunk[3] = { g, 4 + g, g };                // xh, xl, xh

    for (int h = 0; h < 64; ++h) {
        const int bb = h & 1;
        // ---- issue global x loads for h+1 ----
        float vn[2][4];
        if (h < 63) {
            const unsigned gadd = (unsigned)(h + 1) * 125u;
#pragma unroll
            for (int j = 0; j < 2; ++j) {
#pragma unroll
                for (int e = 0; e < 4; ++e) {
                    int t = q_[j] * 4 + e;
                    vn[j][e] = (t < 25) ? xin[gb[j] + gadd + e] : 0.f;
                }
            }
        }

        // ---- B-frags for this h (L2) ----
        v8bf bfr[3];
#pragma unroll
        for (int s = 0; s < 3; ++s)
            bfr[s] = *(const v8bf*)&Bn[h * 96 + s * 32 + g * 8];

        // ---- A-frags + MFMA ----
        const us16* xp = xpan[bb];
#pragma unroll
        for (int mt = 0; mt < 4; ++mt) {
            int r  = mt * 16 + c;
            int rb = r * 64;
            int rx = r & 7;
#pragma unroll
            for (int s = 0; s < 3; ++s) {
                v8bf a = *(const v8bf*)&xp[rb + ((achunk[s] ^ rx) << 3)];
                acc[mt] = __builtin_amdgcn_mfma_f32_16x16x32_bf16(a, bfr[s], acc[mt], 0, 0, 0);
            }
        }

        // ---- write stage h+1 ----
        if (h < 63) {
            const int nb = bb ^ 1;
#pragma unroll
            for (int j = 0; j < 2; ++j) {
                ushort4 hv, lv;
                hv.x = bf_hi(vn[j][0]); hv.y = bf_hi(vn[j][1]); hv.z = bf_hi(vn[j][2]); hv.w = bf_hi(vn[j][3]);
                lv.x = bf_lo(vn[j][0]); lv.y = bf_lo(vn[j][1]); lv.z = bf_lo(vn[j][2]); lv.w = bf_lo(vn[j][3]);
                *(ushort4*)&xpan[nb][ahi[j]] = hv;
                *(ushort4*)&xpan[nb][alo[j]] = lv;
            }
        }
        __syncthreads();
    }

    // ---- epilogue: +pb +pe, scalar stores ----
    const int col = w * 16 + c;
    const float pbv = pb[col];
    const float peP[5] = {pe[1], pe[2], pe[3], pe[4], pe[5]};
#pragma unroll
    for (int mt = 0; mt < 4; ++mt) {
#pragma unroll
        for (int reg = 0; reg < 4; ++reg) {
            int grow = brow0 + mt * 16 + g * 4 + reg;
            int smp  = grow / 5;
            int p    = grow - smp * 5;
            x0[((size_t)smp * SEQ + (p + 1)) * 64 + col] = acc[mt][reg] + pbv + peP[p];
        }
    }
}

// ---------------- Kernel 1.5: weight prep ----------------
// tf region (6*98304): Wq_t[192][192] @0, Wo_t[64][192] @36864,
//   W1_t[128][192] @49152, W2_t[64][384] @73728; k-sections [wh|wh|wl].
// proj region (393216): Wpx[n(64)][h(64)][sec(3)][k(32)], k>=25 -> 0.
#define PREP_TF   (6 * 98304)
#define PREP_TOT  (PREP_TF + 393216)

__global__ __launch_bounds__(256) void prep_kernel(
    const float* __restrict__ qkv_w, const float* __restrict__ out_w,
    const float* __restrict__ mlp_w1, const float* __restrict__ mlp_w2,
    const float* __restrict__ proj_w,
    us16* __restrict__ Wext, us16* __restrict__ Wpx)
{
    int gid = blockIdx.x * 256 + threadIdx.x;
    if (gid < PREP_TF) {
        int l = gid / 98304;
        int r = gid - l * 98304;
        int sec; float v;
        if (r < 36864) {
            int n = r / 192, k = r - n * 192; sec = k >> 6; int ks = k & 63;
            v = qkv_w[(size_t)(l * 64 + ks) * 192 + n];
        } else if (r < 49152) {
            int r2 = r - 36864; int n = r2 / 192, k = r2 - n * 192; sec = k >> 6; int ks = k & 63;
            v = out_w[(size_t)(l * 64 + ks) * 64 + n];
        } else if (r < 73728) {
            int r3 = r - 49152; int n = r3 / 192, k = r3 - n * 192; sec = k >> 6; int ks = k & 63;
            v = mlp_w1[(size_t)(l * 64 + ks) * 128 + n];
        } else {
            int r4 = r - 73728; int n = r4 / 384, k = r4 - n * 384; sec = k >> 7; int ks = k & 127;
            v = mlp_w2[(size_t)(l * 128 + ks) * 64 + n];
        }
        Wext[gid] = (sec < 2) ? bf_hi(v) : bf_lo(v);
    } else {
        int r = gid - PREP_TF;
        int n   = r / 6144;
        int rem = r - n * 6144;
        int h   = rem / 96;
        int kk  = rem - h * 96;
        int sec = kk >> 5;
        int k   = kk & 31;
        float v = (k < 25) ? proj_w[(size_t)(h * 25 + k) * 64 + n] : 0.f;
        Wpx[r] = (sec < 2) ? bf_hi(v) : bf_lo(v);
    }
}

// ---------------- Kernel 2: MFMA transformer (UNCHANGED round-6) ----------
#define XS 68
#define HS 136
#define QS 196
#define MS 264

__device__ __forceinline__ float wred64(float v) {
#pragma unroll
    for (int o = 32; o > 0; o >>= 1) v += __shfl_xor(v, o, 64);
    return v;
}

__device__ __forceinline__ void load_a_ke1(const us16* hp, int lane, v8bf a[3][6]) {
    const int g = lane >> 4;
#pragma unroll
    for (int mt = 0; mt < 3; ++mt) {
        int r  = mt * 16 + (lane & 15);
        int rx = r & 7;
        int rb = r * HS;
#pragma unroll
        for (int kt = 0; kt < 6; ++kt) {
            int sec = ((kt >> 1) == 1) ? 1 : 0;
            int c3  = ((kt & 1) << 2) + g;
            a[mt][kt] = *(const v8bf*)&hp[rb + sec * 64 + ((c3 ^ rx) << 3)];
        }
    }
}

__device__ __forceinline__ void ln_to_panel(const float* xp, us16* hp,
                                            const float* g_, const float* b_,
                                            int lane, int w) {
    f4 g4 = *(const f4*)&g_[(lane & 15) * 4];
    f4 b4 = *(const f4*)&b_[(lane & 15) * 4];
#pragma unroll
    for (int it = 0; it < 3; ++it) {
        int r = w * 12 + it * 4 + (lane >> 4);
        f4 xv = *(const f4*)&xp[r * XS + (lane & 15) * 4];
        float s = xv[0] + xv[1] + xv[2] + xv[3];
        s += __shfl_xor(s, 1, 64); s += __shfl_xor(s, 2, 64);
        s += __shfl_xor(s, 4, 64); s += __shfl_xor(s, 8, 64);
        float mean = s * (1.f / 64.f);
        f4 dv = xv - mean;
        float vs = dv[0]*dv[0] + dv[1]*dv[1] + dv[2]*dv[2] + dv[3]*dv[3];
        vs += __shfl_xor(vs, 1, 64); vs += __shfl_xor(vs, 2, 64);
        vs += __shfl_xor(vs, 4, 64); vs += __shfl_xor(vs, 8, 64);
        float rs = rsqrtf(vs * (1.f / 64.f) + 1e-5f);
        f4 h4 = dv * rs * g4 + b4;
        int C0 = (lane & 15) * 4;
        int chunk = C0 >> 3, e = C0 & 7;
        int ad = r * HS + ((chunk ^ (r & 7)) << 3) + e;
        ushort4 hi, lo;
        hi.x = bf_hi(h4[0]); hi.y = bf_hi(h4[1]); hi.z = bf_hi(h4[2]); hi.w = bf_hi(h4[3]);
        lo.x = bf_lo(h4[0]); lo.y = bf_lo(h4[1]); lo.z = bf_lo(h4[2]); lo.w = bf_lo(h4[3]);
        *(ushort4*)&hp[ad]      = hi;
        *(ushort4*)&hp[ad + 64] = lo;
    }
}

__global__ __launch_bounds__(256, 2) void tf2_kernel(
    const float* __restrict__ x0buf,
    const us16*  __restrict__ Wext,
    const float* __restrict__ qkv_b, const float* __restrict__ out_b,
    const float* __restrict__ ln1_g, const float* __restrict__ ln1_b,
    const float* __restrict__ ln2_g, const float* __restrict__ ln2_b,
    const float* __restrict__ mlp_b1, const float* __restrict__ mlp_b2,
    const float* __restrict__ head_g, const float* __restrict__ head_b,
    const float* __restrict__ head_w, const float* __restrict__ head_bias,
    float* __restrict__ out)
{
    __shared__ __align__(16) float x_lds[48 * XS];
    __shared__ __align__(16) us16  h_lds[48 * HS];
    __shared__ __align__(16) unsigned char u_buf[48 * MS * 2];
    __shared__ __align__(16) float att_lds[8 * 4 * 36];

    float* qkv_lds = (float*)u_buf;
    us16*  m_lds   = (us16*)u_buf;

    const int tid  = threadIdx.x;
    const int lane = tid & 63;
    const int w    = tid >> 6;
    const int bid  = blockIdx.x;

#pragma unroll
    for (int j = 0; j < 3; ++j) {
        int idx = tid + j * 256;
        int row = idx >> 4, c4 = idx & 15;
        *(f4*)&x_lds[row * XS + c4 * 4] =
            *(const f4*)&x0buf[((size_t)bid * 48 + row) * 64 + c4 * 4];
    }
    __syncthreads();

    for (int lay = 0; lay < NLAYER; ++lay) {
        const int lb = lay * 98304;

        ln_to_panel(x_lds, h_lds, ln1_g + lay * 64, ln1_b + lay * 64, lane, w);
        __syncthreads();

        {
            v8bf a[3][6];
            load_a_ke1(h_lds, lane, a);
            const us16* Bq = Wext + lb;
            const float* qb = qkv_b + lay * 192;
            const int g = lane >> 4;
#pragma unroll
            for (int ntl = 0; ntl < 3; ++ntl) {
                int nt = w * 3 + ntl;
                int C  = nt * 16 + (lane & 15);
                v4f acc0 = {0.f,0.f,0.f,0.f}, acc1 = acc0, acc2 = acc0;
#pragma unroll
                for (int kt = 0; kt < 6; ++kt) {
                    v8bf b = *(const v8bf*)&Bq[C * 192 + kt * 32 + g * 8];
                    acc0 = __builtin_amdgcn_mfma_f32_16x16x32_bf16(a[0][kt], b, acc0, 0, 0, 0);
                    acc1 = __builtin_amdgcn_mfma_f32_16x16x32_bf16(a[1][kt], b, acc1, 0, 0, 0);
                    acc2 = __builtin_amdgcn_mfma_f32_16x16x32_bf16(a[2][kt], b, acc2, 0, 0, 0);
                }
                float bias = qb[C];
#pragma unroll
                for (int reg = 0; reg < 4; ++reg) {
                    int rr = g * 4 + reg;
                    qkv_lds[(0 * 16 + rr) * QS + C]  = acc0[reg] + bias;
                    qkv_lds[(1 * 16 + rr) * QS + C]  = acc1[reg] + bias;
                    qkv_lds[(2 * 16 + rr) * QS + C]  = acc2[reg] + bias;
                }
            }
        }
        __syncthreads();

        if (tid < 192) {
            int a8 = tid / 24, rem = tid - a8 * 24;
            int hh = rem / 6, i = rem - hh * 6;
            int rb = a8 * 6;
            const float* qrow = &qkv_lds[(rb + i) * QS + hh * 16];
            f4 q0 = *(const f4*)&qrow[0],  q1 = *(const f4*)&qrow[4];
            f4 q2 = *(const f4*)&qrow[8],  q3 = *(const f4*)&qrow[12];
            float sc[6];
#pragma unroll
            for (int j = 0; j < 6; ++j) {
                const float* kr = &qkv_lds[(rb + j) * QS + 64 + hh * 16];
                f4 k0 = *(const f4*)&kr[0], k1 = *(const f4*)&kr[4];
                f4 k2 = *(const f4*)&kr[8], k3 = *(const f4*)&kr[12];
                f4 p = q0 * k0 + q1 * k1 + q2 * k2 + q3 * k3;
                sc[j] = (p[0] + p[1] + p[2] + p[3]) * 0.25f;
            }
            float mx = sc[0];
#pragma unroll
            for (int j = 1; j < 6; ++j) mx = fmaxf(mx, sc[j]);
            float e[6], sum = 0.f;
#pragma unroll
            for (int j = 0; j < 6; ++j) { e[j] = expf(sc[j] - mx); sum += e[j]; }
            float inv = 1.f / sum;
            float* ap = &att_lds[((a8 * 4 + hh) * 6 + i) * 6];
#pragma unroll
            for (int j = 0; j < 6; ++j) ap[j] = e[j] * inv;
        }
        __syncthreads();

        {
            int cg = tid & 15, rgrp = tid >> 4;
            int hh = cg >> 2;
#pragma unroll
            for (int k = 0; k < 3; ++k) {
                int r = rgrp + 16 * k;
                int a8 = r / 6, i = r - a8 * 6;
                int rb = a8 * 6;
                const float* ap = &att_lds[((a8 * 4 + hh) * 6 + i) * 6];
                f4 o = {0.f,0.f,0.f,0.f};
#pragma unroll
                for (int j = 0; j < 6; ++j)
                    o += ap[j] * *(const f4*)&qkv_lds[(rb + j) * QS + 128 + cg * 4];
                int C0 = cg * 4;
                int chunk = C0 >> 3, e = C0 & 7;
                int ad = r * HS + ((chunk ^ (r & 7)) << 3) + e;
                ushort4 hi, lo;
                hi.x = bf_hi(o[0]); hi.y = bf_hi(o[1]); hi.z = bf_hi(o[2]); hi.w = bf_hi(o[3]);
                lo.x = bf_lo(o[0]); lo.y = bf_lo(o[1]); lo.z = bf_lo(o[2]); lo.w = bf_lo(o[3]);
                *(ushort4*)&h_lds[ad]      = hi;
                *(ushort4*)&h_lds[ad + 64] = lo;
            }
        }
        __syncthreads();

        {
            v8bf a[3][6];
            load_a_ke1(h_lds, lane, a);
            const us16* Bo = Wext + lb + 36864;
            const int g = lane >> 4;
            int C = w * 16 + (lane & 15);
            v4f acc0 = {0.f,0.f,0.f,0.f}, acc1 = acc0, acc2 = acc0;
#pragma unroll
            for (int kt = 0; kt < 6; ++kt) {
                v8bf b = *(const v8bf*)&Bo[C * 192 + kt * 32 + g * 8];
                acc0 = __builtin_amdgcn_mfma_f32_16x16x32_bf16(a[0][kt], b, acc0, 0, 0, 0);
                acc1 = __builtin_amdgcn_mfma_f32_16x16x32_bf16(a[1][kt], b, acc1, 0, 0, 0);
                acc2 = __builtin_amdgcn_mfma_f32_16x16x32_bf16(a[2][kt], b, acc2, 0, 0, 0);
            }
            float bias = out_b[lay * 64 + C];
#pragma unroll
            for (int reg = 0; reg < 4; ++reg) {
                int rr = g * 4 + reg;
                x_lds[(0 * 16 + rr) * XS + C] += acc0[reg] + bias;
                x_lds[(1 * 16 + rr) * XS + C] += acc1[reg] + bias;
                x_lds[(2 * 16 + rr) * XS + C] += acc2[reg] + bias;
            }
        }
        __syncthreads();

        ln_to_panel(x_lds, h_lds, ln2_g + lay * 64, ln2_b + lay * 64, lane, w);
        __syncthreads();

        {
            v8bf a[3][6];
            load_a_ke1(h_lds, lane, a);
            const us16* B1 = Wext + lb + 49152;
            const float* b1 = mlp_b1 + lay * 128;
            const int g = lane >> 4;
#pragma unroll
            for (int q = 0; q < 2; ++q) {
                int nt = w * 2 + q;
                int C  = nt * 16 + (lane & 15);
                v4f acc0 = {0.f,0.f,0.f,0.f}, acc1 = acc0, acc2 = acc0;
#pragma unroll
                for (int kt = 0; kt < 6; ++kt) {
                    v8bf b = *(const v8bf*)&B1[C * 192 + kt * 32 + g * 8];
                    acc0 = __builtin_amdgcn_mfma_f32_16x16x32_bf16(a[0][kt], b, acc0, 0, 0, 0);
                    acc1 = __builtin_amdgcn_mfma_f32_16x16x32_bf16(a[1][kt], b, acc1, 0, 0, 0);
                    acc2 = __builtin_amdgcn_mfma_f32_16x16x32_bf16(a[2][kt], b, acc2, 0, 0, 0);
                }
                float bias = b1[C];
                int ch4 = C >> 3, e = C & 7;
#pragma unroll
                for (int mt = 0; mt < 3; ++mt) {
                    v4f acc = (mt == 0) ? acc0 : ((mt == 1) ? acc1 : acc2);
#pragma unroll
                    for (int reg = 0; reg < 4; ++reg) {
                        int row = mt * 16 + g * 4 + reg;
                        float u = acc[reg] + bias;
                        float gl = 0.5f * u * (1.f + erff(u * 0.70710678118654752f));
                        int ad = row * MS + ((ch4 ^ (row & 7)) << 3) + e;
                        m_lds[ad]       = bf_hi(gl);
                        m_lds[ad + 128] = bf_lo(gl);
                    }
                }
            }
        }
        __syncthreads();

        {
            v8bf a[3][12];
            const int g = lane >> 4;
#pragma unroll
            for (int mt = 0; mt < 3; ++mt) {
                int r  = mt * 16 + (lane & 15);
                int rx = r & 7;
                int rb = r * MS;
#pragma unroll
                for (int kt = 0; kt < 12; ++kt) {
                    int sec = (kt >> 2);
                    int off = (sec == 1) ? 128 : 0;
                    int c4  = ((kt & 3) << 2) + g;
                    a[mt][kt] = *(const v8bf*)&m_lds[rb + off + ((c4 ^ rx) << 3)];
                }
            }
            const us16* B2 = Wext + lb + 73728;
            int C = w * 16 + (lane & 15);
            v4f acc0 = {0.f,0.f,0.f,0.f}, acc1 = acc0, acc2 = acc0;
#pragma unroll
            for (int kt = 0; kt < 12; ++kt) {
                v8bf b = *(const v8bf*)&B2[C * 384 + kt * 32 + g * 8];
                acc0 = __builtin_amdgcn_mfma_f32_16x16x32_bf16(a[0][kt], b, acc0, 0, 0, 0);
                acc1 = __builtin_amdgcn_mfma_f32_16x16x32_bf16(a[1][kt], b, acc1, 0, 0, 0);
                acc2 = __builtin_amdgcn_mfma_f32_16x16x32_bf16(a[2][kt], b, acc2, 0, 0, 0);
            }
            float bias = mlp_b2[lay * 64 + C];
#pragma unroll
            for (int reg = 0; reg < 4; ++reg) {
                int rr = g * 4 + reg;
                x_lds[(0 * 16 + rr) * XS + C] += acc0[reg] + bias;
                x_lds[(1 * 16 + rr) * XS + C] += acc1[reg] + bias;
                x_lds[(2 * 16 + rr) * XS + C] += acc2[reg] + bias;
            }
        }
        __syncthreads();
    }

#pragma unroll
    for (int si = 0; si < 2; ++si) {
        int s = w * 2 + si;
        float val = x_lds[(s * 6) * XS + lane];
        float m  = wred64(val) * (1.f / 64.f);
        float dv = val - m;
        float var = wred64(dv * dv) * (1.f / 64.f);
        float hh  = dv * rsqrtf(var + 1e-5f) * head_g[lane] + head_b[lane];
        float l0  = wred64(hh * head_w[lane * 2 + 0]);
        float l1  = wred64(hh * head_w[lane * 2 + 1]);
        if (lane == 0) {
            l0 += head_bias[0];
            l1 += head_bias[1];
            float mx = fmaxf(l0, l1);
            float e0 = expf(l0 - mx), e1 = expf(l1 - mx);
            float inv = 1.f / (e0 + e1);
            out[(size_t)(bid * 8 + s) * 2 + 0] = e0 * inv;
            out[(size_t)(bid * 8 + s) * 2 + 1] = e1 * inv;
        }
    }
}

// ---------------- launch ----------------
extern "C" void kernel_launch(void* const* d_in, const int* in_sizes, int n_in,
                              void* d_out, int out_size, void* d_ws, size_t ws_size,
                              hipStream_t stream) {
    const float* xin     = (const float*)d_in[0];
    const float* proj_w  = (const float*)d_in[1];
    const float* proj_b  = (const float*)d_in[2];
    const float* cls     = (const float*)d_in[3];
    const float* pe      = (const float*)d_in[4];
    const float* qkv_w   = (const float*)d_in[5];
    const float* qkv_b   = (const float*)d_in[6];
    const float* out_w   = (const float*)d_in[7];
    const float* out_b   = (const float*)d_in[8];
    const float* ln1_g   = (const float*)d_in[9];
    const float* ln1_b   = (const float*)d_in[10];
    const float* ln2_g   = (const float*)d_in[11];
    const float* ln2_b   = (const float*)d_in[12];
    const float* mlp_w1  = (const float*)d_in[13];
    const float* mlp_b1  = (const float*)d_in[14];
    const float* mlp_w2  = (const float*)d_in[15];
    const float* mlp_b2  = (const float*)d_in[16];
    const float* head_g  = (const float*)d_in[17];
    const float* head_b  = (const float*)d_in[18];
    const float* head_w  = (const float*)d_in[19];
    const float* head_bs = (const float*)d_in[20];
    float* outp = (float*)d_out;

    float* x0   = (float*)d_ws;                               // 25,165,824 B
    us16*  Wext = (us16*)((char*)d_ws + 25165824);            //  2,359,296 B
    us16*  Wpx  = (us16*)((char*)d_ws + 25165824 + 2359296);  //    786,432 B

    prep_kernel<<<PREP_TOT / 256, 256, 0, stream>>>(
        qkv_w, out_w, mlp_w1, mlp_w2, proj_w, Wext, Wpx);

    proj2_kernel<<<PB2 + 16, 256, 0, stream>>>(
        xin, Wpx, proj_b, cls, pe, x0);

    tf2_kernel<<<B_TOT / 8, 256, 0, stream>>>(
        x0, Wext, qkv_b, out_b, ln1_g, ln1_b, ln2_g, ln2_b,
        mlp_b1, mlp_b2, head_g, head_b, head_w, head_bs, outp);
}

// Round 8
// 1187.894 us; speedup vs baseline: 2.0256x; 1.0284x over previous
//
#include <hip/hip_runtime.h>
#include <hip/hip_bf16.h>
#include <math.h>

// ---------------------------------------------------------------------------
// EEG-ViT forward. Round 8.
// FIX: tf2 u_buf was 25,344 B but qkv panel needs 37,632 B -> OOB ds ops
//   zeroed K/V for samples 6-7 of each block (absmax 0.0078 artifact).
// proj2: x staging now float4 (q<6) / scalar (q==6) loads; q==7 pad quads
//   zero-filled once in prologue and skipped in the h-loop.
// tf2 otherwise UNCHANGED from round 7.
// ---------------------------------------------------------------------------

#define B_TOT   16384
#define SEQ     6
#define NLAYER  6

typedef float f4 __attribute__((ext_vector_type(4)));
typedef float f4u __attribute__((ext_vector_type(4), aligned(4)));
typedef float v4f __attribute__((ext_vector_type(4)));
typedef __bf16 v8bf __attribute__((ext_vector_type(8)));
typedef unsigned short us16;

__device__ __forceinline__ us16 bf_hi(float v) {
    __bf16 h = (__bf16)v; return __builtin_bit_cast(us16, h);
}
__device__ __forceinline__ us16 bf_lo(float v) {
    __bf16 h = (__bf16)v;
    float rem = v - (float)h;
    __bf16 l = (__bf16)rem;
    return __builtin_bit_cast(us16, l);
}

// ---------------- Kernel 1: MFMA projection ----------------
#define PB2 1280   // 64 patch-rows per block

__global__ __launch_bounds__(256) void proj2_kernel(
    const float* __restrict__ xin,   // (B, 8000)
    const us16*  __restrict__ Wpx,   // (64 n, 64 h, 3 sec, 32 k)
    const float* __restrict__ pb,    // (64)
    const float* __restrict__ cls,   // (64)
    const float* __restrict__ pe,    // (6)
    float* __restrict__ x0)          // (B, 6, 64)
{
    const int tid = threadIdx.x;
    const int blk = blockIdx.x;

    if (blk >= PB2) {
        // ---- cls rows ----
        const float pe0 = pe[0];
        const f4* cls4 = (const f4*)cls;
        f4 cv[16];
#pragma unroll
        for (int j = 0; j < 16; ++j) cv[j] = cls4[j] + pe0;
        int r0 = (blk - PB2) * 1024 + tid * 4;
#pragma unroll
        for (int rr = 0; rr < 4; ++rr) {
            f4* dst = (f4*)(x0 + (size_t)(r0 + rr) * 384);
#pragma unroll
            for (int j = 0; j < 16; ++j) dst[j] = cv[j];
        }
        return;
    }

    __shared__ __align__(16) us16 xpan[2][64 * 64];   // 2 x 8 KB

    const int lane = tid & 63;
    const int w    = tid >> 6;        // wave = n-tile
    const int c    = lane & 15;
    const int g    = lane >> 4;
    const int brow0 = blk * 64;

    // ---- staging precompute: 2 quad-groups per thread ----
    // group idx (0..511): row = idx>>3, q = idx&7; covers t = q*4..q*4+3
    // q<6: full float4; q==6: t=24 scalar + 3 pad; q==7: all pad (zero once).
    unsigned gb[2];      // global float offset excl h*125
    int      q_[2];
    unsigned ahi[2], alo[2];
#pragma unroll
    for (int j = 0; j < 2; ++j) {
        int idx = tid + j * 256;
        int row = idx >> 3, q = idx & 7;
        int grow = brow0 + row;
        int smp = grow / 5;
        int p   = grow - smp * 5;
        gb[j] = (unsigned)smp * 8000u + (unsigned)p * 25u + (unsigned)(q * 4);
        q_[j] = q;
        int ch_hi = q >> 1;
        int ch_lo = (q >> 1) + 4;
        ahi[j] = (unsigned)(row * 64 + (((ch_hi ^ (row & 7))) << 3) + (q & 1) * 4);
        alo[j] = (unsigned)(row * 64 + (((ch_lo ^ (row & 7))) << 3) + (q & 1) * 4);
    }

    v4f acc[4];
#pragma unroll
    for (int mt = 0; mt < 4; ++mt) acc[mt] = (v4f){0.f, 0.f, 0.f, 0.f};

    // ---- prologue: zero pad quads in BOTH buffers, stage h=0 ----
    {
        const ushort4 z = {0, 0, 0, 0};
#pragma unroll
        for (int j = 0; j < 2; ++j) {
            if (q_[j] == 7) {
                *(ushort4*)&xpan[0][ahi[j]] = z;  *(ushort4*)&xpan[0][alo[j]] = z;
                *(ushort4*)&xpan[1][ahi[j]] = z;  *(ushort4*)&xpan[1][alo[j]] = z;
            } else {
                float v[4];
                if (q_[j] < 6) {
                    f4u t = *(const f4u*)&xin[gb[j]];
                    v[0] = t[0]; v[1] = t[1]; v[2] = t[2]; v[3] = t[3];
                } else {
                    v[0] = xin[gb[j]]; v[1] = v[2] = v[3] = 0.f;
                }
                ushort4 hv, lv;
                hv.x = bf_hi(v[0]); hv.y = bf_hi(v[1]); hv.z = bf_hi(v[2]); hv.w = bf_hi(v[3]);
                lv.x = bf_lo(v[0]); lv.y = bf_lo(v[1]); lv.z = bf_lo(v[2]); lv.w = bf_lo(v[3]);
                *(ushort4*)&xpan[0][ahi[j]] = hv;
                *(ushort4*)&xpan[0][alo[j]] = lv;
            }
        }
    }
    __syncthreads();

    const us16* Bn = Wpx + (size_t)(w * 16 + c) * 6144;   // [h][3][32]
    const int achunk[3] = { g, 4 + g, g };                // xh, xl, xh

    for (int h = 0; h < 64; ++h) {
        const int bb = h & 1;
        // ---- issue global x loads for h+1 ----
        float vn[2][4];
        if (h < 63) {
            const unsigned gadd = (unsigned)(h + 1) * 125u;
#pragma unroll
            for (int j = 0; j < 2; ++j) {
                if (q_[j] < 6) {
                    f4u t = *(const f4u*)&xin[gb[j] + gadd];
                    vn[j][0] = t[0]; vn[j][1] = t[1]; vn[j][2] = t[2]; vn[j][3] = t[3];
                } else if (q_[j] == 6) {
                    vn[j][0] = xin[gb[j] + gadd]; vn[j][1] = vn[j][2] = vn[j][3] = 0.f;
                }
            }
        }

        // ---- B-frags for this h (L2) ----
        v8bf bfr[3];
#pragma unroll
        for (int s = 0; s < 3; ++s)
            bfr[s] = *(const v8bf*)&Bn[h * 96 + s * 32 + g * 8];

        // ---- A-frags + MFMA ----
        const us16* xp = xpan[bb];
#pragma unroll
        for (int mt = 0; mt < 4; ++mt) {
            int r  = mt * 16 + c;
            int rb = r * 64;
            int rx = r & 7;
#pragma unroll
            for (int s = 0; s < 3; ++s) {
                v8bf a = *(const v8bf*)&xp[rb + ((achunk[s] ^ rx) << 3)];
                acc[mt] = __builtin_amdgcn_mfma_f32_16x16x32_bf16(a, bfr[s], acc[mt], 0, 0, 0);
            }
        }

        // ---- write stage h+1 ----
        if (h < 63) {
            const int nb = bb ^ 1;
#pragma unroll
            for (int j = 0; j < 2; ++j) {
                if (q_[j] < 7) {
                    ushort4 hv, lv;
                    hv.x = bf_hi(vn[j][0]); hv.y = bf_hi(vn[j][1]); hv.z = bf_hi(vn[j][2]); hv.w = bf_hi(vn[j][3]);
                    lv.x = bf_lo(vn[j][0]); lv.y = bf_lo(vn[j][1]); lv.z = bf_lo(vn[j][2]); lv.w = bf_lo(vn[j][3]);
                    *(ushort4*)&xpan[nb][ahi[j]] = hv;
                    *(ushort4*)&xpan[nb][alo[j]] = lv;
                }
            }
        }
        __syncthreads();
    }

    // ---- epilogue: +pb +pe, scalar stores ----
    const int col = w * 16 + c;
    const float pbv = pb[col];
    const float peP[5] = {pe[1], pe[2], pe[3], pe[4], pe[5]};
#pragma unroll
    for (int mt = 0; mt < 4; ++mt) {
#pragma unroll
        for (int reg = 0; reg < 4; ++reg) {
            int grow = brow0 + mt * 16 + g * 4 + reg;
            int smp  = grow / 5;
            int p    = grow - smp * 5;
            x0[((size_t)smp * SEQ + (p + 1)) * 64 + col] = acc[mt][reg] + pbv + peP[p];
        }
    }
}

// ---------------- Kernel 1.5: weight prep ----------------
#define PREP_TF   (6 * 98304)
#define PREP_TOT  (PREP_TF + 393216)

__global__ __launch_bounds__(256) void prep_kernel(
    const float* __restrict__ qkv_w, const float* __restrict__ out_w,
    const float* __restrict__ mlp_w1, const float* __restrict__ mlp_w2,
    const float* __restrict__ proj_w,
    us16* __restrict__ Wext, us16* __restrict__ Wpx)
{
    int gid = blockIdx.x * 256 + threadIdx.x;
    if (gid < PREP_TF) {
        int l = gid / 98304;
        int r = gid - l * 98304;
        int sec; float v;
        if (r < 36864) {
            int n = r / 192, k = r - n * 192; sec = k >> 6; int ks = k & 63;
            v = qkv_w[(size_t)(l * 64 + ks) * 192 + n];
        } else if (r < 49152) {
            int r2 = r - 36864; int n = r2 / 192, k = r2 - n * 192; sec = k >> 6; int ks = k & 63;
            v = out_w[(size_t)(l * 64 + ks) * 64 + n];
        } else if (r < 73728) {
            int r3 = r - 49152; int n = r3 / 192, k = r3 - n * 192; sec = k >> 6; int ks = k & 63;
            v = mlp_w1[(size_t)(l * 64 + ks) * 128 + n];
        } else {
            int r4 = r - 73728; int n = r4 / 384, k = r4 - n * 384; sec = k >> 7; int ks = k & 127;
            v = mlp_w2[(size_t)(l * 128 + ks) * 64 + n];
        }
        Wext[gid] = (sec < 2) ? bf_hi(v) : bf_lo(v);
    } else {
        int r = gid - PREP_TF;
        int n   = r / 6144;
        int rem = r - n * 6144;
        int h   = rem / 96;
        int kk  = rem - h * 96;
        int sec = kk >> 5;
        int k   = kk & 31;
        float v = (k < 25) ? proj_w[(size_t)(h * 25 + k) * 64 + n] : 0.f;
        Wpx[r] = (sec < 2) ? bf_hi(v) : bf_lo(v);
    }
}

// ---------------- Kernel 2: MFMA transformer ----------------
#define XS 68
#define HS 136
#define QS 196
#define MS 264

__device__ __forceinline__ float wred64(float v) {
#pragma unroll
    for (int o = 32; o > 0; o >>= 1) v += __shfl_xor(v, o, 64);
    return v;
}

__device__ __forceinline__ void load_a_ke1(const us16* hp, int lane, v8bf a[3][6]) {
    const int g = lane >> 4;
#pragma unroll
    for (int mt = 0; mt < 3; ++mt) {
        int r  = mt * 16 + (lane & 15);
        int rx = r & 7;
        int rb = r * HS;
#pragma unroll
        for (int kt = 0; kt < 6; ++kt) {
            int sec = ((kt >> 1) == 1) ? 1 : 0;
            int c3  = ((kt & 1) << 2) + g;
            a[mt][kt] = *(const v8bf*)&hp[rb + sec * 64 + ((c3 ^ rx) << 3)];
        }
    }
}

__device__ __forceinline__ void ln_to_panel(const float* xp, us16* hp,
                                            const float* g_, const float* b_,
                                            int lane, int w) {
    f4 g4 = *(const f4*)&g_[(lane & 15) * 4];
    f4 b4 = *(const f4*)&b_[(lane & 15) * 4];
#pragma unroll
    for (int it = 0; it < 3; ++it) {
        int r = w * 12 + it * 4 + (lane >> 4);
        f4 xv = *(const f4*)&xp[r * XS + (lane & 15) * 4];
        float s = xv[0] + xv[1] + xv[2] + xv[3];
        s += __shfl_xor(s, 1, 64); s += __shfl_xor(s, 2, 64);
        s += __shfl_xor(s, 4, 64); s += __shfl_xor(s, 8, 64);
        float mean = s * (1.f / 64.f);
        f4 dv = xv - mean;
        float vs = dv[0]*dv[0] + dv[1]*dv[1] + dv[2]*dv[2] + dv[3]*dv[3];
        vs += __shfl_xor(vs, 1, 64); vs += __shfl_xor(vs, 2, 64);
        vs += __shfl_xor(vs, 4, 64); vs += __shfl_xor(vs, 8, 64);
        float rs = rsqrtf(vs * (1.f / 64.f) + 1e-5f);
        f4 h4 = dv * rs * g4 + b4;
        int C0 = (lane & 15) * 4;
        int chunk = C0 >> 3, e = C0 & 7;
        int ad = r * HS + ((chunk ^ (r & 7)) << 3) + e;
        ushort4 hi, lo;
        hi.x = bf_hi(h4[0]); hi.y = bf_hi(h4[1]); hi.z = bf_hi(h4[2]); hi.w = bf_hi(h4[3]);
        lo.x = bf_lo(h4[0]); lo.y = bf_lo(h4[1]); lo.z = bf_lo(h4[2]); lo.w = bf_lo(h4[3]);
        *(ushort4*)&hp[ad]      = hi;
        *(ushort4*)&hp[ad + 64] = lo;
    }
}

__global__ __launch_bounds__(256, 2) void tf2_kernel(
    const float* __restrict__ x0buf,
    const us16*  __restrict__ Wext,
    const float* __restrict__ qkv_b, const float* __restrict__ out_b,
    const float* __restrict__ ln1_g, const float* __restrict__ ln1_b,
    const float* __restrict__ ln2_g, const float* __restrict__ ln2_b,
    const float* __restrict__ mlp_b1, const float* __restrict__ mlp_b2,
    const float* __restrict__ head_g, const float* __restrict__ head_b,
    const float* __restrict__ head_w, const float* __restrict__ head_bias,
    float* __restrict__ out)
{
    __shared__ __align__(16) float x_lds[48 * XS];              // 13,056 B
    __shared__ __align__(16) us16  h_lds[48 * HS];              // 13,056 B
    __shared__ __align__(16) unsigned char u_buf[48 * QS * 4];  // 37,632 B (qkv f32 / m bf16)
    __shared__ __align__(16) float att_lds[8 * 4 * 36];         //  4,608 B

    float* qkv_lds = (float*)u_buf;
    us16*  m_lds   = (us16*)u_buf;

    const int tid  = threadIdx.x;
    const int lane = tid & 63;
    const int w    = tid >> 6;
    const int bid  = blockIdx.x;

#pragma unroll
    for (int j = 0; j < 3; ++j) {
        int idx = tid + j * 256;
        int row = idx >> 4, c4 = idx & 15;
        *(f4*)&x_lds[row * XS + c4 * 4] =
            *(const f4*)&x0buf[((size_t)bid * 48 + row) * 64 + c4 * 4];
    }
    __syncthreads();

    for (int lay = 0; lay < NLAYER; ++lay) {
        const int lb = lay * 98304;

        ln_to_panel(x_lds, h_lds, ln1_g + lay * 64, ln1_b + lay * 64, lane, w);
        __syncthreads();

        {
            v8bf a[3][6];
            load_a_ke1(h_lds, lane, a);
            const us16* Bq = Wext + lb;
            const float* qb = qkv_b + lay * 192;
            const int g = lane >> 4;
#pragma unroll
            for (int ntl = 0; ntl < 3; ++ntl) {
                int nt = w * 3 + ntl;
                int C  = nt * 16 + (lane & 15);
                v4f acc0 = {0.f,0.f,0.f,0.f}, acc1 = acc0, acc2 = acc0;
#pragma unroll
                for (int kt = 0; kt < 6; ++kt) {
                    v8bf b = *(const v8bf*)&Bq[C * 192 + kt * 32 + g * 8];
                    acc0 = __builtin_amdgcn_mfma_f32_16x16x32_bf16(a[0][kt], b, acc0, 0, 0, 0);
                    acc1 = __builtin_amdgcn_mfma_f32_16x16x32_bf16(a[1][kt], b, acc1, 0, 0, 0);
                    acc2 = __builtin_amdgcn_mfma_f32_16x16x32_bf16(a[2][kt], b, acc2, 0, 0, 0);
                }
                float bias = qb[C];
#pragma unroll
                for (int reg = 0; reg < 4; ++reg) {
                    int rr = g * 4 + reg;
                    qkv_lds[(0 * 16 + rr) * QS + C]  = acc0[reg] + bias;
                    qkv_lds[(1 * 16 + rr) * QS + C]  = acc1[reg] + bias;
                    qkv_lds[(2 * 16 + rr) * QS + C]  = acc2[reg] + bias;
                }
            }
        }
        __syncthreads();

        if (tid < 192) {
            int a8 = tid / 24, rem = tid - a8 * 24;
            int hh = rem / 6, i = rem - hh * 6;
            int rb = a8 * 6;
            const float* qrow = &qkv_lds[(rb + i) * QS + hh * 16];
            f4 q0 = *(const f4*)&qrow[0],  q1 = *(const f4*)&qrow[4];
            f4 q2 = *(const f4*)&qrow[8],  q3 = *(const f4*)&qrow[12];
            float sc[6];
#pragma unroll
            for (int j = 0; j < 6; ++j) {
                const float* kr = &qkv_lds[(rb + j) * QS + 64 + hh * 16];
                f4 k0 = *(const f4*)&kr[0], k1 = *(const f4*)&kr[4];
                f4 k2 = *(const f4*)&kr[8], k3 = *(const f4*)&kr[12];
                f4 p = q0 * k0 + q1 * k1 + q2 * k2 + q3 * k3;
                sc[j] = (p[0] + p[1] + p[2] + p[3]) * 0.25f;
            }
            float mx = sc[0];
#pragma unroll
            for (int j = 1; j < 6; ++j) mx = fmaxf(mx, sc[j]);
            float e[6], sum = 0.f;
#pragma unroll
            for (int j = 0; j < 6; ++j) { e[j] = expf(sc[j] - mx); sum += e[j]; }
            float inv = 1.f / sum;
            float* ap = &att_lds[((a8 * 4 + hh) * 6 + i) * 6];
#pragma unroll
            for (int j = 0; j < 6; ++j) ap[j] = e[j] * inv;
        }
        __syncthreads();

        {
            int cg = tid & 15, rgrp = tid >> 4;
            int hh = cg >> 2;
#pragma unroll
            for (int k = 0; k < 3; ++k) {
                int r = rgrp + 16 * k;
                int a8 = r / 6, i = r - a8 * 6;
                int rb = a8 * 6;
                const float* ap = &att_lds[((a8 * 4 + hh) * 6 + i) * 6];
                f4 o = {0.f,0.f,0.f,0.f};
#pragma unroll
                for (int j = 0; j < 6; ++j)
                    o += ap[j] * *(const f4*)&qkv_lds[(rb + j) * QS + 128 + cg * 4];
                int C0 = cg * 4;
                int chunk = C0 >> 3, e = C0 & 7;
                int ad = r * HS + ((chunk ^ (r & 7)) << 3) + e;
                ushort4 hi, lo;
                hi.x = bf_hi(o[0]); hi.y = bf_hi(o[1]); hi.z = bf_hi(o[2]); hi.w = bf_hi(o[3]);
                lo.x = bf_lo(o[0]); lo.y = bf_lo(o[1]); lo.z = bf_lo(o[2]); lo.w = bf_lo(o[3]);
                *(ushort4*)&h_lds[ad]      = hi;
                *(ushort4*)&h_lds[ad + 64] = lo;
            }
        }
        __syncthreads();

        {
            v8bf a[3][6];
            load_a_ke1(h_lds, lane, a);
            const us16* Bo = Wext + lb + 36864;
            const int g = lane >> 4;
            int C = w * 16 + (lane & 15);
            v4f acc0 = {0.f,0.f,0.f,0.f}, acc1 = acc0, acc2 = acc0;
#pragma unroll
            for (int kt = 0; kt < 6; ++kt) {
                v8bf b = *(const v8bf*)&Bo[C * 192 + kt * 32 + g * 8];
                acc0 = __builtin_amdgcn_mfma_f32_16x16x32_bf16(a[0][kt], b, acc0, 0, 0, 0);
                acc1 = __builtin_amdgcn_mfma_f32_16x16x32_bf16(a[1][kt], b, acc1, 0, 0, 0);
                acc2 = __builtin_amdgcn_mfma_f32_16x16x32_bf16(a[2][kt], b, acc2, 0, 0, 0);
            }
            float bias = out_b[lay * 64 + C];
#pragma unroll
            for (int reg = 0; reg < 4; ++reg) {
                int rr = g * 4 + reg;
                x_lds[(0 * 16 + rr) * XS + C] += acc0[reg] + bias;
                x_lds[(1 * 16 + rr) * XS + C] += acc1[reg] + bias;
                x_lds[(2 * 16 + rr) * XS + C] += acc2[reg] + bias;
            }
        }
        __syncthreads();

        ln_to_panel(x_lds, h_lds, ln2_g + lay * 64, ln2_b + lay * 64, lane, w);
        __syncthreads();

        {
            v8bf a[3][6];
            load_a_ke1(h_lds, lane, a);
            const us16* B1 = Wext + lb + 49152;
            const float* b1 = mlp_b1 + lay * 128;
            const int g = lane >> 4;
#pragma unroll
            for (int q = 0; q < 2; ++q) {
                int nt = w * 2 + q;
                int C  = nt * 16 + (lane & 15);
                v4f acc0 = {0.f,0.f,0.f,0.f}, acc1 = acc0, acc2 = acc0;
#pragma unroll
                for (int kt = 0; kt < 6; ++kt) {
                    v8bf b = *(const v8bf*)&B1[C * 192 + kt * 32 + g * 8];
                    acc0 = __builtin_amdgcn_mfma_f32_16x16x32_bf16(a[0][kt], b, acc0, 0, 0, 0);
                    acc1 = __builtin_amdgcn_mfma_f32_16x16x32_bf16(a[1][kt], b, acc1, 0, 0, 0);
                    acc2 = __builtin_amdgcn_mfma_f32_16x16x32_bf16(a[2][kt], b, acc2, 0, 0, 0);
                }
                float bias = b1[C];
                int ch4 = C >> 3, e = C & 7;
#pragma unroll
                for (int mt = 0; mt < 3; ++mt) {
                    v4f acc = (mt == 0) ? acc0 : ((mt == 1) ? acc1 : acc2);
#pragma unroll
                    for (int reg = 0; reg < 4; ++reg) {
                        int row = mt * 16 + g * 4 + reg;
                        float u = acc[reg] + bias;
                        float gl = 0.5f * u * (1.f + erff(u * 0.70710678118654752f));
                        int ad = row * MS + ((ch4 ^ (row & 7)) << 3) + e;
                        m_lds[ad]       = bf_hi(gl);
                        m_lds[ad + 128] = bf_lo(gl);
                    }
                }
            }
        }
        __syncthreads();

        {
            v8bf a[3][12];
            const int g = lane >> 4;
#pragma unroll
            for (int mt = 0; mt < 3; ++mt) {
                int r  = mt * 16 + (lane & 15);
                int rx = r & 7;
                int rb = r * MS;
#pragma unroll
                for (int kt = 0; kt < 12; ++kt) {
                    int sec = (kt >> 2);
                    int off = (sec == 1) ? 128 : 0;
                    int c4  = ((kt & 3) << 2) + g;
                    a[mt][kt] = *(const v8bf*)&m_lds[rb + off + ((c4 ^ rx) << 3)];
                }
            }
            const us16* B2 = Wext + lb + 73728;
            int C = w * 16 + (lane & 15);
            v4f acc0 = {0.f,0.f,0.f,0.f}, acc1 = acc0, acc2 = acc0;
#pragma unroll
            for (int kt = 0; kt < 12; ++kt) {
                v8bf b = *(const v8bf*)&B2[C * 384 + kt * 32 + g * 8];
                acc0 = __builtin_amdgcn_mfma_f32_16x16x32_bf16(a[0][kt], b, acc0, 0, 0, 0);
                acc1 = __builtin_amdgcn_mfma_f32_16x16x32_bf16(a[1][kt], b, acc1, 0, 0, 0);
                acc2 = __builtin_amdgcn_mfma_f32_16x16x32_bf16(a[2][kt], b, acc2, 0, 0, 0);
            }
            float bias = mlp_b2[lay * 64 + C];
#pragma unroll
            for (int reg = 0; reg < 4; ++reg) {
                int rr = g * 4 + reg;
                x_lds[(0 * 16 + rr) * XS + C] += acc0[reg] + bias;
                x_lds[(1 * 16 + rr) * XS + C] += acc1[reg] + bias;
                x_lds[(2 * 16 + rr) * XS + C] += acc2[reg] + bias;
            }
        }
        __syncthreads();
    }

#pragma unroll
    for (int si = 0; si < 2; ++si) {
        int s = w * 2 + si;
        float val = x_lds[(s * 6) * XS + lane];
        float m  = wred64(val) * (1.f / 64.f);
        float dv = val - m;
        float var = wred64(dv * dv) * (1.f / 64.f);
        float hh  = dv * rsqrtf(var + 1e-5f) * head_g[lane] + head_b[lane];
        float l0  = wred64(hh * head_w[lane * 2 + 0]);
        float l1  = wred64(hh * head_w[lane * 2 + 1]);
        if (lane == 0) {
            l0 += head_bias[0];
            l1 += head_bias[1];
            float mx = fmaxf(l0, l1);
            float e0 = expf(l0 - mx), e1 = expf(l1 - mx);
            float inv = 1.f / (e0 + e1);
            out[(size_t)(bid * 8 + s) * 2 + 0] = e0 * inv;
            out[(size_t)(bid * 8 + s) * 2 + 1] = e1 * inv;
        }
    }
}

// ---------------- launch ----------------
extern "C" void kernel_launch(void* const* d_in, const int* in_sizes, int n_in,
                              void* d_out, int out_size, void* d_ws, size_t ws_size,
                              hipStream_t stream) {
    const float* xin     = (const float*)d_in[0];
    const float* proj_w  = (const float*)d_in[1];
    const float* proj_b  = (const float*)d_in[2];
    const float* cls     = (const float*)d_in[3];
    const float* pe      = (const float*)d_in[4];
    const float* qkv_w   = (const float*)d_in[5];
    const float* qkv_b   = (const float*)d_in[6];
    const float* out_w   = (const float*)d_in[7];
    const float* out_b   = (const float*)d_in[8];
    const float* ln1_g   = (const float*)d_in[9];
    const float* ln1_b   = (const float*)d_in[10];
    const float* ln2_g   = (const float*)d_in[11];
    const float* ln2_b   = (const float*)d_in[12];
    const float* mlp_w1  = (const float*)d_in[13];
    const float* mlp_b1  = (const float*)d_in[14];
    const float* mlp_w2  = (const float*)d_in[15];
    const float* mlp_b2  = (const float*)d_in[16];
    const float* head_g  = (const float*)d_in[17];
    const float* head_b  = (const float*)d_in[18];
    const float* head_w  = (const float*)d_in[19];
    const float* head_bs = (const float*)d_in[20];
    float* outp = (float*)d_out;

    float* x0   = (float*)d_ws;                               // 25,165,824 B
    us16*  Wext = (us16*)((char*)d_ws + 25165824);            //  2,359,296 B
    us16*  Wpx  = (us16*)((char*)d_ws + 25165824 + 2359296);  //    786,432 B

    prep_kernel<<<PREP_TOT / 256, 256, 0, stream>>>(
        qkv_w, out_w, mlp_w1, mlp_w2, proj_w, Wext, Wpx);

    proj2_kernel<<<PB2 + 16, 256, 0, stream>>>(
        xin, Wpx, proj_b, cls, pe, x0);

    tf2_kernel<<<B_TOT / 8, 256, 0, stream>>>(
        x0, Wext, qkv_b, out_b, ln1_g, ln1_b, ln2_g, ln2_b,
        mlp_b1, mlp_b2, head_g, head_b, head_w, head_bs, outp);
}

// Round 9
// 1185.712 us; speedup vs baseline: 2.0293x; 1.0018x over previous
//
#include <hip/hip_runtime.h>
#include <hip/hip_bf16.h>
#include <math.h>

// ---------------------------------------------------------------------------
// EEG-ViT forward. Round 9.
// tf2: MFMA operands SWAPPED (A=weights row=n, B=activations col=row) so each
//   lane's 4 accs are 4 consecutive N for one activation row -> all GEMM
//   epilogues become vectorized conflict-free f4/b64 LDS writes (kills the
//   4.78e7 bank conflicts from column-scattered scalar stores).
// proj2 / prep: UNCHANGED from round 8 (validated).
// ---------------------------------------------------------------------------

#define B_TOT   16384
#define SEQ     6
#define NLAYER  6

typedef float f4 __attribute__((ext_vector_type(4)));
typedef float f4u __attribute__((ext_vector_type(4), aligned(4)));
typedef float v4f __attribute__((ext_vector_type(4)));
typedef __bf16 v8bf __attribute__((ext_vector_type(8)));
typedef unsigned short us16;

__device__ __forceinline__ us16 bf_hi(float v) {
    __bf16 h = (__bf16)v; return __builtin_bit_cast(us16, h);
}
__device__ __forceinline__ us16 bf_lo(float v) {
    __bf16 h = (__bf16)v;
    float rem = v - (float)h;
    __bf16 l = (__bf16)rem;
    return __builtin_bit_cast(us16, l);
}

// ---------------- Kernel 1: MFMA projection (unchanged r8) ----------------
#define PB2 1280   // 64 patch-rows per block

__global__ __launch_bounds__(256) void proj2_kernel(
    const float* __restrict__ xin, const us16* __restrict__ Wpx,
    const float* __restrict__ pb, const float* __restrict__ cls,
    const float* __restrict__ pe, float* __restrict__ x0)
{
    const int tid = threadIdx.x;
    const int blk = blockIdx.x;

    if (blk >= PB2) {
        const float pe0 = pe[0];
        const f4* cls4 = (const f4*)cls;
        f4 cv[16];
#pragma unroll
        for (int j = 0; j < 16; ++j) cv[j] = cls4[j] + pe0;
        int r0 = (blk - PB2) * 1024 + tid * 4;
#pragma unroll
        for (int rr = 0; rr < 4; ++rr) {
            f4* dst = (f4*)(x0 + (size_t)(r0 + rr) * 384);
#pragma unroll
            for (int j = 0; j < 16; ++j) dst[j] = cv[j];
        }
        return;
    }

    __shared__ __align__(16) us16 xpan[2][64 * 64];

    const int lane = tid & 63;
    const int w    = tid >> 6;
    const int c    = lane & 15;
    const int g    = lane >> 4;
    const int brow0 = blk * 64;

    unsigned gb[2];
    int      q_[2];
    unsigned ahi[2], alo[2];
#pragma unroll
    for (int j = 0; j < 2; ++j) {
        int idx = tid + j * 256;
        int row = idx >> 3, q = idx & 7;
        int grow = brow0 + row;
        int smp = grow / 5;
        int p   = grow - smp * 5;
        gb[j] = (unsigned)smp * 8000u + (unsigned)p * 25u + (unsigned)(q * 4);
        q_[j] = q;
        int ch_hi = q >> 1;
        int ch_lo = (q >> 1) + 4;
        ahi[j] = (unsigned)(row * 64 + (((ch_hi ^ (row & 7))) << 3) + (q & 1) * 4);
        alo[j] = (unsigned)(row * 64 + (((ch_lo ^ (row & 7))) << 3) + (q & 1) * 4);
    }

    v4f acc[4];
#pragma unroll
    for (int mt = 0; mt < 4; ++mt) acc[mt] = (v4f){0.f, 0.f, 0.f, 0.f};

    {
        const ushort4 z = {0, 0, 0, 0};
#pragma unroll
        for (int j = 0; j < 2; ++j) {
            if (q_[j] == 7) {
                *(ushort4*)&xpan[0][ahi[j]] = z;  *(ushort4*)&xpan[0][alo[j]] = z;
                *(ushort4*)&xpan[1][ahi[j]] = z;  *(ushort4*)&xpan[1][alo[j]] = z;
            } else {
                float v[4];
                if (q_[j] < 6) {
                    f4u t = *(const f4u*)&xin[gb[j]];
                    v[0] = t[0]; v[1] = t[1]; v[2] = t[2]; v[3] = t[3];
                } else {
                    v[0] = xin[gb[j]]; v[1] = v[2] = v[3] = 0.f;
                }
                ushort4 hv, lv;
                hv.x = bf_hi(v[0]); hv.y = bf_hi(v[1]); hv.z = bf_hi(v[2]); hv.w = bf_hi(v[3]);
                lv.x = bf_lo(v[0]); lv.y = bf_lo(v[1]); lv.z = bf_lo(v[2]); lv.w = bf_lo(v[3]);
                *(ushort4*)&xpan[0][ahi[j]] = hv;
                *(ushort4*)&xpan[0][alo[j]] = lv;
            }
        }
    }
    __syncthreads();

    const us16* Bn = Wpx + (size_t)(w * 16 + c) * 6144;
    const int achunk[3] = { g, 4 + g, g };

    for (int h = 0; h < 64; ++h) {
        const int bb = h & 1;
        float vn[2][4];
        if (h < 63) {
            const unsigned gadd = (unsigned)(h + 1) * 125u;
#pragma unroll
            for (int j = 0; j < 2; ++j) {
                if (q_[j] < 6) {
                    f4u t = *(const f4u*)&xin[gb[j] + gadd];
                    vn[j][0] = t[0]; vn[j][1] = t[1]; vn[j][2] = t[2]; vn[j][3] = t[3];
                } else if (q_[j] == 6) {
                    vn[j][0] = xin[gb[j] + gadd]; vn[j][1] = vn[j][2] = vn[j][3] = 0.f;
                }
            }
        }

        v8bf bfr[3];
#pragma unroll
        for (int s = 0; s < 3; ++s)
            bfr[s] = *(const v8bf*)&Bn[h * 96 + s * 32 + g * 8];

        const us16* xp = xpan[bb];
#pragma unroll
        for (int mt = 0; mt < 4; ++mt) {
            int r  = mt * 16 + c;
            int rb = r * 64;
            int rx = r & 7;
#pragma unroll
            for (int s = 0; s < 3; ++s) {
                v8bf a = *(const v8bf*)&xp[rb + ((achunk[s] ^ rx) << 3)];
                acc[mt] = __builtin_amdgcn_mfma_f32_16x16x32_bf16(a, bfr[s], acc[mt], 0, 0, 0);
            }
        }

        if (h < 63) {
            const int nb = bb ^ 1;
#pragma unroll
            for (int j = 0; j < 2; ++j) {
                if (q_[j] < 7) {
                    ushort4 hv, lv;
                    hv.x = bf_hi(vn[j][0]); hv.y = bf_hi(vn[j][1]); hv.z = bf_hi(vn[j][2]); hv.w = bf_hi(vn[j][3]);
                    lv.x = bf_lo(vn[j][0]); lv.y = bf_lo(vn[j][1]); lv.z = bf_lo(vn[j][2]); lv.w = bf_lo(vn[j][3]);
                    *(ushort4*)&xpan[nb][ahi[j]] = hv;
                    *(ushort4*)&xpan[nb][alo[j]] = lv;
                }
            }
        }
        __syncthreads();
    }

    const int col = w * 16 + c;
    const float pbv = pb[col];
    const float peP[5] = {pe[1], pe[2], pe[3], pe[4], pe[5]};
#pragma unroll
    for (int mt = 0; mt < 4; ++mt) {
#pragma unroll
        for (int reg = 0; reg < 4; ++reg) {
            int grow = brow0 + mt * 16 + g * 4 + reg;
            int smp  = grow / 5;
            int p    = grow - smp * 5;
            x0[((size_t)smp * SEQ + (p + 1)) * 64 + col] = acc[mt][reg] + pbv + peP[p];
        }
    }
}

// ---------------- Kernel 1.5: weight prep (unchanged r8) ----------------
#define PREP_TF   (6 * 98304)
#define PREP_TOT  (PREP_TF + 393216)

__global__ __launch_bounds__(256) void prep_kernel(
    const float* __restrict__ qkv_w, const float* __restrict__ out_w,
    const float* __restrict__ mlp_w1, const float* __restrict__ mlp_w2,
    const float* __restrict__ proj_w,
    us16* __restrict__ Wext, us16* __restrict__ Wpx)
{
    int gid = blockIdx.x * 256 + threadIdx.x;
    if (gid < PREP_TF) {
        int l = gid / 98304;
        int r = gid - l * 98304;
        int sec; float v;
        if (r < 36864) {
            int n = r / 192, k = r - n * 192; sec = k >> 6; int ks = k & 63;
            v = qkv_w[(size_t)(l * 64 + ks) * 192 + n];
        } else if (r < 49152) {
            int r2 = r - 36864; int n = r2 / 192, k = r2 - n * 192; sec = k >> 6; int ks = k & 63;
            v = out_w[(size_t)(l * 64 + ks) * 64 + n];
        } else if (r < 73728) {
            int r3 = r - 49152; int n = r3 / 192, k = r3 - n * 192; sec = k >> 6; int ks = k & 63;
            v = mlp_w1[(size_t)(l * 64 + ks) * 128 + n];
        } else {
            int r4 = r - 73728; int n = r4 / 384, k = r4 - n * 384; sec = k >> 7; int ks = k & 127;
            v = mlp_w2[(size_t)(l * 128 + ks) * 64 + n];
        }
        Wext[gid] = (sec < 2) ? bf_hi(v) : bf_lo(v);
    } else {
        int r = gid - PREP_TF;
        int n   = r / 6144;
        int rem = r - n * 6144;
        int h   = rem / 96;
        int kk  = rem - h * 96;
        int sec = kk >> 5;
        int k   = kk & 31;
        float v = (k < 25) ? proj_w[(size_t)(h * 25 + k) * 64 + n] : 0.f;
        Wpx[r] = (sec < 2) ? bf_hi(v) : bf_lo(v);
    }
}

// ---------------- Kernel 2: MFMA transformer (operand-swapped) ------------
#define XS 68
#define HS 136
#define QS 196
#define MS 264

__device__ __forceinline__ float wred64(float v) {
#pragma unroll
    for (int o = 32; o > 0; o >>= 1) v += __shfl_xor(v, o, 64);
    return v;
}

// B-operand loader (activations): col=lane&15 -> act row, k-window = lane>>4.
// Reads the hi/lo 64-col panel, KE=192 mapping [xh|xl|xh].
__device__ __forceinline__ void load_bact(const us16* hp, int lane, v8bf b[3][6]) {
    const int g = lane >> 4;
#pragma unroll
    for (int ct = 0; ct < 3; ++ct) {
        int r  = ct * 16 + (lane & 15);
        int rx = r & 7;
        int rb = r * HS;
#pragma unroll
        for (int kt = 0; kt < 6; ++kt) {
            int sec = ((kt >> 1) == 1) ? 1 : 0;
            int c3  = ((kt & 1) << 2) + g;
            b[ct][kt] = *(const v8bf*)&hp[rb + sec * 64 + ((c3 ^ rx) << 3)];
        }
    }
}

__device__ __forceinline__ void ln_to_panel(const float* xp, us16* hp,
                                            const float* g_, const float* b_,
                                            int lane, int w) {
    f4 g4 = *(const f4*)&g_[(lane & 15) * 4];
    f4 b4 = *(const f4*)&b_[(lane & 15) * 4];
#pragma unroll
    for (int it = 0; it < 3; ++it) {
        int r = w * 12 + it * 4 + (lane >> 4);
        f4 xv = *(const f4*)&xp[r * XS + (lane & 15) * 4];
        float s = xv[0] + xv[1] + xv[2] + xv[3];
        s += __shfl_xor(s, 1, 64); s += __shfl_xor(s, 2, 64);
        s += __shfl_xor(s, 4, 64); s += __shfl_xor(s, 8, 64);
        float mean = s * (1.f / 64.f);
        f4 dv = xv - mean;
        float vs = dv[0]*dv[0] + dv[1]*dv[1] + dv[2]*dv[2] + dv[3]*dv[3];
        vs += __shfl_xor(vs, 1, 64); vs += __shfl_xor(vs, 2, 64);
        vs += __shfl_xor(vs, 4, 64); vs += __shfl_xor(vs, 8, 64);
        float rs = rsqrtf(vs * (1.f / 64.f) + 1e-5f);
        f4 h4 = dv * rs * g4 + b4;
        int C0 = (lane & 15) * 4;
        int chunk = C0 >> 3, e = C0 & 7;
        int ad = r * HS + ((chunk ^ (r & 7)) << 3) + e;
        ushort4 hi, lo;
        hi.x = bf_hi(h4[0]); hi.y = bf_hi(h4[1]); hi.z = bf_hi(h4[2]); hi.w = bf_hi(h4[3]);
        lo.x = bf_lo(h4[0]); lo.y = bf_lo(h4[1]); lo.z = bf_lo(h4[2]); lo.w = bf_lo(h4[3]);
        *(ushort4*)&hp[ad]      = hi;
        *(ushort4*)&hp[ad + 64] = lo;
    }
}

__global__ __launch_bounds__(256, 2) void tf2_kernel(
    const float* __restrict__ x0buf,
    const us16*  __restrict__ Wext,
    const float* __restrict__ qkv_b, const float* __restrict__ out_b,
    const float* __restrict__ ln1_g, const float* __restrict__ ln1_b,
    const float* __restrict__ ln2_g, const float* __restrict__ ln2_b,
    const float* __restrict__ mlp_b1, const float* __restrict__ mlp_b2,
    const float* __restrict__ head_g, const float* __restrict__ head_b,
    const float* __restrict__ head_w, const float* __restrict__ head_bias,
    float* __restrict__ out)
{
    __shared__ __align__(16) float x_lds[48 * XS];              // 13,056 B
    __shared__ __align__(16) us16  h_lds[48 * HS];              // 13,056 B
    __shared__ __align__(16) unsigned char u_buf[48 * QS * 4];  // 37,632 B
    __shared__ __align__(16) float att_lds[8 * 4 * 36];         //  4,608 B

    float* qkv_lds = (float*)u_buf;
    us16*  m_lds   = (us16*)u_buf;

    const int tid  = threadIdx.x;
    const int lane = tid & 63;
    const int w    = tid >> 6;
    const int c    = lane & 15;      // act-row within col-tile / weight-n within n-tile
    const int g    = lane >> 4;      // k-window / n-subgroup
    const int bid  = blockIdx.x;

#pragma unroll
    for (int j = 0; j < 3; ++j) {
        int idx = tid + j * 256;
        int row = idx >> 4, c4 = idx & 15;
        *(f4*)&x_lds[row * XS + c4 * 4] =
            *(const f4*)&x0buf[((size_t)bid * 48 + row) * 64 + c4 * 4];
    }
    __syncthreads();

    for (int lay = 0; lay < NLAYER; ++lay) {
        const int lb = lay * 98304;

        // ---- P0: LN1 -> h panel ----
        ln_to_panel(x_lds, h_lds, ln1_g + lay * 64, ln1_b + lay * 64, lane, w);
        __syncthreads();

        // ---- P1: QKV GEMM. A=Wq (row=n), B=act (col=row). ----
        {
            v8bf bact[3][6];
            load_bact(h_lds, lane, bact);
            const us16* Aq = Wext + lb;
            const float* qb = qkv_b + lay * 192;
#pragma unroll
            for (int ntl = 0; ntl < 3; ++ntl) {
                int nt = w * 3 + ntl;
                v4f acc0 = {0.f,0.f,0.f,0.f}, acc1 = acc0, acc2 = acc0;
#pragma unroll
                for (int kt = 0; kt < 6; ++kt) {
                    v8bf a = *(const v8bf*)&Aq[(nt * 16 + c) * 192 + kt * 32 + g * 8];
                    acc0 = __builtin_amdgcn_mfma_f32_16x16x32_bf16(a, bact[0][kt], acc0, 0, 0, 0);
                    acc1 = __builtin_amdgcn_mfma_f32_16x16x32_bf16(a, bact[1][kt], acc1, 0, 0, 0);
                    acc2 = __builtin_amdgcn_mfma_f32_16x16x32_bf16(a, bact[2][kt], acc2, 0, 0, 0);
                }
                f4 bias = *(const f4*)&qb[nt * 16 + g * 4];
                *(f4*)&qkv_lds[(0 * 16 + c) * QS + nt * 16 + g * 4] = acc0 + bias;
                *(f4*)&qkv_lds[(1 * 16 + c) * QS + nt * 16 + g * 4] = acc1 + bias;
                *(f4*)&qkv_lds[(2 * 16 + c) * QS + nt * 16 + g * 4] = acc2 + bias;
            }
        }
        __syncthreads();

        // ---- P2: scores + softmax (unchanged) ----
        if (tid < 192) {
            int a8 = tid / 24, rem = tid - a8 * 24;
            int hh = rem / 6, i = rem - hh * 6;
            int rb = a8 * 6;
            const float* qrow = &qkv_lds[(rb + i) * QS + hh * 16];
            f4 q0 = *(const f4*)&qrow[0],  q1 = *(const f4*)&qrow[4];
            f4 q2 = *(const f4*)&qrow[8],  q3 = *(const f4*)&qrow[12];
            float sc[6];
#pragma unroll
            for (int j = 0; j < 6; ++j) {
                const float* kr = &qkv_lds[(rb + j) * QS + 64 + hh * 16];
                f4 k0 = *(const f4*)&kr[0], k1 = *(const f4*)&kr[4];
                f4 k2 = *(const f4*)&kr[8], k3 = *(const f4*)&kr[12];
                f4 p = q0 * k0 + q1 * k1 + q2 * k2 + q3 * k3;
                sc[j] = (p[0] + p[1] + p[2] + p[3]) * 0.25f;
            }
            float mx = sc[0];
#pragma unroll
            for (int j = 1; j < 6; ++j) mx = fmaxf(mx, sc[j]);
            float e[6], sum = 0.f;
#pragma unroll
            for (int j = 0; j < 6; ++j) { e[j] = expf(sc[j] - mx); sum += e[j]; }
            float inv = 1.f / sum;
            float* ap = &att_lds[((a8 * 4 + hh) * 6 + i) * 6];
#pragma unroll
            for (int j = 0; j < 6; ++j) ap[j] = e[j] * inv;
        }
        __syncthreads();

        // ---- P3: PV -> o panel (unchanged) ----
        {
            int cg = tid & 15, rgrp = tid >> 4;
            int hh = cg >> 2;
#pragma unroll
            for (int k = 0; k < 3; ++k) {
                int r = rgrp + 16 * k;
                int a8 = r / 6, i = r - a8 * 6;
                int rb = a8 * 6;
                const float* ap = &att_lds[((a8 * 4 + hh) * 6 + i) * 6];
                f4 o = {0.f,0.f,0.f,0.f};
#pragma unroll
                for (int j = 0; j < 6; ++j)
                    o += ap[j] * *(const f4*)&qkv_lds[(rb + j) * QS + 128 + cg * 4];
                int C0 = cg * 4;
                int chunk = C0 >> 3, e = C0 & 7;
                int ad = r * HS + ((chunk ^ (r & 7)) << 3) + e;
                ushort4 hi, lo;
                hi.x = bf_hi(o[0]); hi.y = bf_hi(o[1]); hi.z = bf_hi(o[2]); hi.w = bf_hi(o[3]);
                lo.x = bf_lo(o[0]); lo.y = bf_lo(o[1]); lo.z = bf_lo(o[2]); lo.w = bf_lo(o[3]);
                *(ushort4*)&h_lds[ad]      = hi;
                *(ushort4*)&h_lds[ad + 64] = lo;
            }
        }
        __syncthreads();

        // ---- P4: out-proj GEMM + residual. A=Wo, B=o. ----
        {
            v8bf bact[3][6];
            load_bact(h_lds, lane, bact);
            const us16* Ao = Wext + lb + 36864;
            v4f acc0 = {0.f,0.f,0.f,0.f}, acc1 = acc0, acc2 = acc0;
#pragma unroll
            for (int kt = 0; kt < 6; ++kt) {
                v8bf a = *(const v8bf*)&Ao[(w * 16 + c) * 192 + kt * 32 + g * 8];
                acc0 = __builtin_amdgcn_mfma_f32_16x16x32_bf16(a, bact[0][kt], acc0, 0, 0, 0);
                acc1 = __builtin_amdgcn_mfma_f32_16x16x32_bf16(a, bact[1][kt], acc1, 0, 0, 0);
                acc2 = __builtin_amdgcn_mfma_f32_16x16x32_bf16(a, bact[2][kt], acc2, 0, 0, 0);
            }
            f4 bias = *(const f4*)&out_b[lay * 64 + w * 16 + g * 4];
            f4* p0 = (f4*)&x_lds[(0 * 16 + c) * XS + w * 16 + g * 4];
            f4* p1 = (f4*)&x_lds[(1 * 16 + c) * XS + w * 16 + g * 4];
            f4* p2 = (f4*)&x_lds[(2 * 16 + c) * XS + w * 16 + g * 4];
            *p0 += acc0 + bias;
            *p1 += acc1 + bias;
            *p2 += acc2 + bias;
        }
        __syncthreads();

        // ---- P5: LN2 -> h panel ----
        ln_to_panel(x_lds, h_lds, ln2_g + lay * 64, ln2_b + lay * 64, lane, w);
        __syncthreads();

        // ---- P6: MLP1 GEMM + GELU -> m panel. A=W1, B=act. ----
        {
            v8bf bact[3][6];
            load_bact(h_lds, lane, bact);
            const us16* A1 = Wext + lb + 49152;
            const float* b1 = mlp_b1 + lay * 128;
#pragma unroll
            for (int q = 0; q < 2; ++q) {
                int nt = w * 2 + q;
                v4f acc0 = {0.f,0.f,0.f,0.f}, acc1 = acc0, acc2 = acc0;
#pragma unroll
                for (int kt = 0; kt < 6; ++kt) {
                    v8bf a = *(const v8bf*)&A1[(nt * 16 + c) * 192 + kt * 32 + g * 8];
                    acc0 = __builtin_amdgcn_mfma_f32_16x16x32_bf16(a, bact[0][kt], acc0, 0, 0, 0);
                    acc1 = __builtin_amdgcn_mfma_f32_16x16x32_bf16(a, bact[1][kt], acc1, 0, 0, 0);
                    acc2 = __builtin_amdgcn_mfma_f32_16x16x32_bf16(a, bact[2][kt], acc2, 0, 0, 0);
                }
                f4 bias = *(const f4*)&b1[nt * 16 + g * 4];
                int col0 = nt * 16 + g * 4;
                int ch   = col0 >> 3;
                int sub  = col0 & 7;          // 0 or 4
#pragma unroll
                for (int ct = 0; ct < 3; ++ct) {
                    v4f acc = (ct == 0) ? acc0 : ((ct == 1) ? acc1 : acc2);
                    f4 u = acc + bias;
                    float gl[4];
#pragma unroll
                    for (int e = 0; e < 4; ++e)
                        gl[e] = 0.5f * u[e] * (1.f + erff(u[e] * 0.70710678118654752f));
                    int row = ct * 16 + c;
                    int ad  = row * MS + ((ch ^ (row & 7)) << 3) + sub;
                    ushort4 hi, lo;
                    hi.x = bf_hi(gl[0]); hi.y = bf_hi(gl[1]); hi.z = bf_hi(gl[2]); hi.w = bf_hi(gl[3]);
                    lo.x = bf_lo(gl[0]); lo.y = bf_lo(gl[1]); lo.z = bf_lo(gl[2]); lo.w = bf_lo(gl[3]);
                    *(ushort4*)&m_lds[ad]       = hi;
                    *(ushort4*)&m_lds[ad + 128] = lo;
                }
            }
        }
        __syncthreads();

        // ---- P7: MLP2 GEMM + residual. A=W2 (KE=384), B=m. ----
        {
            v8bf bact[3][12];
#pragma unroll
            for (int ct = 0; ct < 3; ++ct) {
                int r  = ct * 16 + c;
                int rx = r & 7;
                int rb = r * MS;
#pragma unroll
                for (int kt = 0; kt < 12; ++kt) {
                    int sec = (kt >> 2);
                    int off = (sec == 1) ? 128 : 0;
                    int c4  = ((kt & 3) << 2) + g;
                    bact[ct][kt] = *(const v8bf*)&m_lds[rb + off + ((c4 ^ rx) << 3)];
                }
            }
            const us16* A2 = Wext + lb + 73728;
            v4f acc0 = {0.f,0.f,0.f,0.f}, acc1 = acc0, acc2 = acc0;
#pragma unroll
            for (int kt = 0; kt < 12; ++kt) {
                v8bf a = *(const v8bf*)&A2[(w * 16 + c) * 384 + kt * 32 + g * 8];
                acc0 = __builtin_amdgcn_mfma_f32_16x16x32_bf16(a, bact[0][kt], acc0, 0, 0, 0);
                acc1 = __builtin_amdgcn_mfma_f32_16x16x32_bf16(a, bact[1][kt], acc1, 0, 0, 0);
                acc2 = __builtin_amdgcn_mfma_f32_16x16x32_bf16(a, bact[2][kt], acc2, 0, 0, 0);
            }
            f4 bias = *(const f4*)&mlp_b2[lay * 64 + w * 16 + g * 4];
            f4* p0 = (f4*)&x_lds[(0 * 16 + c) * XS + w * 16 + g * 4];
            f4* p1 = (f4*)&x_lds[(1 * 16 + c) * XS + w * 16 + g * 4];
            f4* p2 = (f4*)&x_lds[(2 * 16 + c) * XS + w * 16 + g * 4];
            *p0 += acc0 + bias;
            *p1 += acc1 + bias;
            *p2 += acc2 + bias;
        }
        __syncthreads();
    }

    // ---- head: LN(cls rows) -> 2-class softmax ----
#pragma unroll
    for (int si = 0; si < 2; ++si) {
        int s = w * 2 + si;
        float val = x_lds[(s * 6) * XS + lane];
        float m  = wred64(val) * (1.f / 64.f);
        float dv = val - m;
        float var = wred64(dv * dv) * (1.f / 64.f);
        float hh  = dv * rsqrtf(var + 1e-5f) * head_g[lane] + head_b[lane];
        float l0  = wred64(hh * head_w[lane * 2 + 0]);
        float l1  = wred64(hh * head_w[lane * 2 + 1]);
        if (lane == 0) {
            l0 += head_bias[0];
            l1 += head_bias[1];
            float mx = fmaxf(l0, l1);
            float e0 = expf(l0 - mx), e1 = expf(l1 - mx);
            float inv = 1.f / (e0 + e1);
            out[(size_t)(bid * 8 + s) * 2 + 0] = e0 * inv;
            out[(size_t)(bid * 8 + s) * 2 + 1] = e1 * inv;
        }
    }
}

// ---------------- launch ----------------
extern "C" void kernel_launch(void* const* d_in, const int* in_sizes, int n_in,
                              void* d_out, int out_size, void* d_ws, size_t ws_size,
                              hipStream_t stream) {
    const float* xin     = (const float*)d_in[0];
    const float* proj_w  = (const float*)d_in[1];
    const float* proj_b  = (const float*)d_in[2];
    const float* cls     = (const float*)d_in[3];
    const float* pe      = (const float*)d_in[4];
    const float* qkv_w   = (const float*)d_in[5];
    const float* qkv_b   = (const float*)d_in[6];
    const float* out_w   = (const float*)d_in[7];
    const float* out_b   = (const float*)d_in[8];
    const float* ln1_g   = (const float*)d_in[9];
    const float* ln1_b   = (const float*)d_in[10];
    const float* ln2_g   = (const float*)d_in[11];
    const float* ln2_b   = (const float*)d_in[12];
    const float* mlp_w1  = (const float*)d_in[13];
    const float* mlp_b1  = (const float*)d_in[14];
    const float* mlp_w2  = (const float*)d_in[15];
    const float* mlp_b2  = (const float*)d_in[16];
    const float* head_g  = (const float*)d_in[17];
    const float* head_b  = (const float*)d_in[18];
    const float* head_w  = (const float*)d_in[19];
    const float* head_bs = (const float*)d_in[20];
    float* outp = (float*)d_out;

    float* x0   = (float*)d_ws;                               // 25,165,824 B
    us16*  Wext = (us16*)((char*)d_ws + 25165824);            //  2,359,296 B
    us16*  Wpx  = (us16*)((char*)d_ws + 25165824 + 2359296);  //    786,432 B

    prep_kernel<<<PREP_TOT / 256, 256, 0, stream>>>(
        qkv_w, out_w, mlp_w1, mlp_w2, proj_w, Wext, Wpx);

    proj2_kernel<<<PB2 + 16, 256, 0, stream>>>(
        xin, Wpx, proj_b, cls, pe, x0);

    tf2_kernel<<<B_TOT / 8, 256, 0, stream>>>(
        x0, Wext, qkv_b, out_b, ln1_g, ln1_b, ln2_g, ln2_b,
        mlp_b1, mlp_b2, head_g, head_b, head_w, head_bs, outp);
}